// Round 4
// baseline (531.141 us; speedup 1.0000x reference)
//
#include <hip/hip_runtime.h>
#include <math.h>

#define NN 50000
#define EE 800000
#define GG 1000

typedef __attribute__((ext_vector_type(2))) _Float16 h2f;
typedef __attribute__((ext_vector_type(4))) _Float16 h4f;
typedef __attribute__((ext_vector_type(8))) _Float16 h8f;
typedef __attribute__((ext_vector_type(4))) float f32x4;

static inline int ceil_div(int a, int b) { return (a + b - 1) / b; }

// ---------------- counting-sort of edges by dst (+ ea permute to f16) ----------------

__global__ __launch_bounds__(256) void hist_k(const int* __restrict__ ei, int* __restrict__ cnt)
{
    int e = blockIdx.x * 256 + threadIdx.x;
    if (e >= EE) return;
    atomicAdd(&cnt[ei[EE + e]], 1);
}

__global__ __launch_bounds__(1024) void scan1_k(const int* __restrict__ cnt, int n,
                                                int* __restrict__ rowptr, int* __restrict__ bsum)
{
    __shared__ int tmp[1024];
    const int tid = threadIdx.x;
    const int i = blockIdx.x * 1024 + tid;
    tmp[tid] = (i < n) ? cnt[i] : 0;
    __syncthreads();
    for (int off = 1; off < 1024; off <<= 1) {
        int t = (tid >= off) ? tmp[tid - off] : 0;
        __syncthreads();
        tmp[tid] += t;
        __syncthreads();
    }
    if (i < n) rowptr[i + 1] = tmp[tid];
    if (tid == 1023) bsum[blockIdx.x] = tmp[1023];
}

__global__ void scan2_k(int* __restrict__ bsum, int nb)
{
    if (threadIdx.x == 0) {
        int run = 0;
        for (int i = 0; i < nb; ++i) { int t = bsum[i]; bsum[i] = run; run += t; }
    }
}

__global__ __launch_bounds__(1024) void scan3_k(int* __restrict__ rowptr,
                                                int* __restrict__ wcur,
                                                const int* __restrict__ bsum, int n)
{
    int i = blockIdx.x * 1024 + threadIdx.x;
    if (i < n) {
        int v = rowptr[i + 1] + bsum[blockIdx.x];
        rowptr[i + 1] = v;
        if (i + 1 < n) wcur[i + 1] = v;
    }
    if (i == 0) { rowptr[0] = 0; wcur[0] = 0; }
}

__global__ __launch_bounds__(256) void scatter_k(const int* __restrict__ ei,
                                                 const float4* __restrict__ ea,
                                                 int* __restrict__ wcur,
                                                 int* __restrict__ srcp,
                                                 h4f* __restrict__ ea_s)
{
    int e = blockIdx.x * 256 + threadIdx.x;
    if (e >= EE) return;
    int dst = ei[EE + e];
    int pos = atomicAdd(&wcur[dst], 1);
    srcp[pos] = ei[e];
    float4 a = ea[e];
    h4f h = {(_Float16)a.x, (_Float16)a.y, (_Float16)a.z, (_Float16)a.w};
    ea_s[pos] = h;
}

// ---------------- f32 -> f16 convert ----------------

__global__ __launch_bounds__(256) void cvt_h(const float* __restrict__ in,
                                             _Float16* __restrict__ out, int n4)
{
    int i = blockIdx.x * 256 + threadIdx.x;
    if (i >= n4) return;
    float4 v = reinterpret_cast<const float4*>(in)[i];
    h4f h = {(_Float16)v.x, (_Float16)v.y, (_Float16)v.z, (_Float16)v.w};
    reinterpret_cast<h4f*>(out)[i] = h;
}

// ---------------- weight shuffle into MFMA A-fragment order ----------------
// wshuf[m][((s*8+c16)*64+lane)*4+j] = w_m[s*16 + (lane>>4)*4 + j][c16*16 + (lane&15)]
struct W4 { const float* w[4]; };

__global__ __launch_bounds__(64) void shuffle_w(W4 ws4, int K, _Float16* __restrict__ out)
{
    const int m = blockIdx.y;
    const int s = blockIdx.x >> 3, c16 = blockIdx.x & 7;
    const int lane = threadIdx.x;
    const float* __restrict__ w = ws4.w[m];
    const int kbase = s * 16 + (lane >> 4) * 4;
    const int col = c16 * 16 + (lane & 15);
    h4f h;
#pragma unroll
    for (int j = 0; j < 4; ++j) h[j] = (_Float16)w[(size_t)(kbase + j) * 128 + col];
    reinterpret_cast<h4f*>(out + (size_t)m * K * 128)[(size_t)blockIdx.x * 64 + lane] = h;
}

// ---------------- fused 4-matrix MFMA GEMM (LDS-staged, vector stores) ----------------
// D = Wfrag(A) x Xfrag(B): D row = HC channel, D col = node  ->  float4/h4f stores
template<int K>
__global__ __launch_bounds__(256) void gemm_mfma(
    const _Float16* __restrict__ xh, const _Float16* __restrict__ wshuf,
    const float* __restrict__ bq, const float* __restrict__ bk,
    const float* __restrict__ bv, const float* __restrict__ bs,
    float* __restrict__ qout, _Float16* __restrict__ kout,
    _Float16* __restrict__ vout, float* __restrict__ skout)
{
    constexpr int KS = K / 16;
    constexpr int PADK = K + 8;              // f16 elems; row stride 2*(K+8) bytes (16B-aligned)
    __shared__ _Float16 xs[64 * PADK];
    const int t = threadIdx.x;
    const int bn = blockIdx.x * 64;
    constexpr int CH = K / 8;                // 16B chunks per row
    for (int idx = t; idx < 64 * CH; idx += 256) {
        const int row = idx / CH, ch = idx % CH;
        h8f val = {0, 0, 0, 0, 0, 0, 0, 0};
        if (bn + row < NN)
            val = reinterpret_cast<const h8f*>(xh + (size_t)(bn + row) * K)[ch];
        *reinterpret_cast<h8f*>(&xs[row * PADK + ch * 8]) = val;
    }
    __syncthreads();

    const int wid = t >> 6, lane = t & 63;
    const int rloc = wid * 16 + (lane & 15);     // local node row (B-frag col / D col)
    const int ko = (lane >> 4) * 4;
    h4f b[KS];
#pragma unroll
    for (int s = 0; s < KS; ++s)
        b[s] = *reinterpret_cast<const h4f*>(&xs[rloc * PADK + s * 16 + ko]);

    const int node = bn + rloc;
    const int hcq = (lane >> 4) * 4;             // HC offset within 16-tile
    const float* bias[4] = {bq, bk, bv, bs};

#pragma unroll
    for (int m = 0; m < 4; ++m) {
        const h4f* __restrict__ wm = reinterpret_cast<const h4f*>(wshuf + (size_t)m * K * 128);
        f32x4 acc[8];
#pragma unroll
        for (int c = 0; c < 8; ++c) acc[c] = {0, 0, 0, 0};
#pragma unroll
        for (int c = 0; c < 8; ++c)
#pragma unroll
            for (int s = 0; s < KS; ++s) {
                h4f af = wm[(s * 8 + c) * 64 + lane];
                acc[c] = __builtin_amdgcn_mfma_f32_16x16x16f16(af, b[s], acc[c], 0, 0, 0);
            }
        if (node < NN) {
            const float* bm = bias[m];
#pragma unroll
            for (int c = 0; c < 8; ++c) {
                const int hc = c * 16 + hcq;
                const float4 bb = *reinterpret_cast<const float4*>(&bm[hc]);
                float o0 = acc[c][0] + bb.x, o1 = acc[c][1] + bb.y;
                float o2 = acc[c][2] + bb.z, o3 = acc[c][3] + bb.w;
                if (m == 0) {
                    float4 o = make_float4(o0, o1, o2, o3);
                    *reinterpret_cast<float4*>(&qout[(size_t)node * 128 + hc]) = o;
                } else if (m == 3) {
                    float4 o = make_float4(o0, o1, o2, o3);
                    *reinterpret_cast<float4*>(&skout[(size_t)node * 128 + hc]) = o;
                } else {
                    h4f oh = {(_Float16)o0, (_Float16)o1, (_Float16)o2, (_Float16)o3};
                    _Float16* dst = (m == 1) ? kout : vout;
                    *reinterpret_cast<h4f*>(&dst[(size_t)node * 128 + hc]) = oh;
                }
            }
        }
    }
}

// ---------------- fused per-node attention aggregation (64-lane wave / node) ----------------

__global__ __launch_bounds__(256) void node_agg(
    const int* __restrict__ rowptr, const int* __restrict__ srcp,
    const h4f* __restrict__ ea_s,
    const float* __restrict__ q, const _Float16* __restrict__ kh,
    const _Float16* __restrict__ vh, const float* __restrict__ we,
    const float* __restrict__ sk, float* __restrict__ hout,
    _Float16* __restrict__ houth, int relu)
{
    const int t = threadIdx.x;
    const int node = blockIdx.x * 4 + (t >> 6);
    if (node >= NN) return;
    const int lane = t & 63;
    const int c0 = lane * 2;                    // 2 channels per lane
    float2 wv[4];
#pragma unroll
    for (int i = 0; i < 4; ++i)
        wv[i] = *reinterpret_cast<const float2*>(&we[i * 128 + c0]);
    const float2 q2 = *reinterpret_cast<const float2*>(&q[(size_t)node * 128 + c0]);
    const int beg = rowptr[node], end = rowptr[node + 1];

    float m = -INFINITY, s = 0.f, a0 = 0.f, a1 = 0.f;

    int p = beg;
    for (; p + 1 < end; p += 2) {
        const int sA = srcp[p], sB = srcp[p + 1];
        const h4f eaA = ea_s[p], eaB = ea_s[p + 1];
        const h2f kA = *reinterpret_cast<const h2f*>(&kh[(size_t)sA * 128 + c0]);
        const h2f kB = *reinterpret_cast<const h2f*>(&kh[(size_t)sB * 128 + c0]);
        const h2f vA = *reinterpret_cast<const h2f*>(&vh[(size_t)sA * 128 + c0]);
        const h2f vB = *reinterpret_cast<const h2f*>(&vh[(size_t)sB * 128 + c0]);
        const float e0A = (float)eaA[0] * wv[0].x + (float)eaA[1] * wv[1].x
                        + (float)eaA[2] * wv[2].x + (float)eaA[3] * wv[3].x;
        const float e1A = (float)eaA[0] * wv[0].y + (float)eaA[1] * wv[1].y
                        + (float)eaA[2] * wv[2].y + (float)eaA[3] * wv[3].y;
        const float e0B = (float)eaB[0] * wv[0].x + (float)eaB[1] * wv[1].x
                        + (float)eaB[2] * wv[2].x + (float)eaB[3] * wv[3].x;
        const float e1B = (float)eaB[0] * wv[0].y + (float)eaB[1] * wv[1].y
                        + (float)eaB[2] * wv[2].y + (float)eaB[3] * wv[3].y;
        float alA = q2.x * ((float)kA[0] + e0A) + q2.y * ((float)kA[1] + e1A);
        float alB = q2.x * ((float)kB[0] + e0B) + q2.y * ((float)kB[1] + e1B);
        alA += __shfl_xor(alA, 1); alA += __shfl_xor(alA, 2);
        alA += __shfl_xor(alA, 4); alA += __shfl_xor(alA, 8);
        alB += __shfl_xor(alB, 1); alB += __shfl_xor(alB, 2);
        alB += __shfl_xor(alB, 4); alB += __shfl_xor(alB, 8);
        alA *= 0.17677669529663687f;
        alB *= 0.17677669529663687f;
        const float mn = fmaxf(m, fmaxf(alA, alB));
        const float r  = __expf(m - mn);
        const float pA = __expf(alA - mn), pB = __expf(alB - mn);
        s = s * r + pA + pB;
        a0 = a0 * r + pA * ((float)vA[0] + e0A) + pB * ((float)vB[0] + e0B);
        a1 = a1 * r + pA * ((float)vA[1] + e1A) + pB * ((float)vB[1] + e1B);
        m = mn;
    }
    if (p < end) {
        const int sA = srcp[p];
        const h4f eaA = ea_s[p];
        const h2f kA = *reinterpret_cast<const h2f*>(&kh[(size_t)sA * 128 + c0]);
        const h2f vA = *reinterpret_cast<const h2f*>(&vh[(size_t)sA * 128 + c0]);
        const float e0A = (float)eaA[0] * wv[0].x + (float)eaA[1] * wv[1].x
                        + (float)eaA[2] * wv[2].x + (float)eaA[3] * wv[3].x;
        const float e1A = (float)eaA[0] * wv[0].y + (float)eaA[1] * wv[1].y
                        + (float)eaA[2] * wv[2].y + (float)eaA[3] * wv[3].y;
        float alA = q2.x * ((float)kA[0] + e0A) + q2.y * ((float)kA[1] + e1A);
        alA += __shfl_xor(alA, 1); alA += __shfl_xor(alA, 2);
        alA += __shfl_xor(alA, 4); alA += __shfl_xor(alA, 8);
        alA *= 0.17677669529663687f;
        const float mn = fmaxf(m, alA);
        const float r  = __expf(m - mn);
        const float pA = __expf(alA - mn);
        s = s * r + pA;
        a0 = a0 * r + pA * ((float)vA[0] + e0A);
        a1 = a1 * r + pA * ((float)vA[1] + e1A);
        m = mn;
    }
    const float inv = 1.0f / (s + 1e-16f);
    const float2 sk2 = *reinterpret_cast<const float2*>(&sk[(size_t)node * 128 + c0]);
    float o0 = a0 * inv + sk2.x;
    float o1 = a1 * inv + sk2.y;
    if (relu) { o0 = fmaxf(o0, 0.f); o1 = fmaxf(o1, 0.f); }
    *reinterpret_cast<float2*>(&hout[(size_t)node * 128 + c0]) = make_float2(o0, o1);
    h2f oh = {(_Float16)o0, (_Float16)o1};
    *reinterpret_cast<h2f*>(&houth[(size_t)node * 128 + c0]) = oh;
}

// ---------------- pooling + head (batch is sorted) ----------------

__global__ __launch_bounds__(256) void boundaries_k(const int* __restrict__ batch,
                                                    int* __restrict__ gptr)
{
    int i = blockIdx.x * 256 + threadIdx.x;
    if (i >= NN) return;
    int b = batch[i];
    int bp = (i == 0) ? -1 : batch[i - 1];
    for (int g = bp + 1; g <= b; ++g) gptr[g] = i;
    if (i == NN - 1) for (int g = b + 1; g <= GG; ++g) gptr[g] = NN;
}

__global__ __launch_bounds__(128) void head_k(
    const float* __restrict__ h, const int* __restrict__ gptr,
    const float* __restrict__ wlin, const float* __restrict__ blin,
    float* __restrict__ out)
{
    __shared__ float red[128];
    const int g = blockIdx.x;
    const int t = threadIdx.x;
    const int beg = gptr[g], end = gptr[g + 1];
    float p = 0.f;
    for (int n = beg; n < end; ++n) p += h[(size_t)n * 128 + t];
    p *= wlin[t];
    red[t] = p;
    __syncthreads();
    for (int off = 64; off; off >>= 1) {
        if (t < off) red[t] += red[t + off];
        __syncthreads();
    }
    if (t == 0) out[g] = red[0] / fmaxf((float)(end - beg), 1.0f) + blin[0];
}

extern "C" void kernel_launch(void* const* d_in, const int* in_sizes, int n_in,
                              void* d_out, int out_size, void* d_ws, size_t ws_size,
                              hipStream_t stream)
{
    const float* x     = (const float*)d_in[0];
    const int*   ei    = (const int*)d_in[1];
    const float* ea    = (const float*)d_in[2];
    const int*   batch = (const int*)d_in[3];
    auto W = [&](int i) { return (const float*)d_in[i]; };

    char* wsb = (char*)d_ws;
    size_t off = 0;
    auto alloc = [&](size_t bytes) { void* p = wsb + off; off += (bytes + 15) & ~15ull; return p; };

    float* q    = (float*)alloc((size_t)NN * 128 * 4);
    float* sk   = (float*)alloc((size_t)NN * 128 * 4);
    float* h1   = (float*)alloc((size_t)NN * 128 * 4);
    float* h2   = (float*)alloc((size_t)NN * 128 * 4);
    h4f* eaS    = (h4f*)alloc((size_t)EE * 8);
    _Float16* kh    = (_Float16*)alloc((size_t)NN * 128 * 2);
    _Float16* vh    = (_Float16*)alloc((size_t)NN * 128 * 2);
    _Float16* hh    = (_Float16*)alloc((size_t)NN * 128 * 2);
    _Float16* wshuf = (_Float16*)alloc((size_t)4 * 128 * 128 * 2);
    int* cnt    = (int*)alloc((size_t)NN * 4);
    int* rowptr = (int*)alloc((size_t)(NN + 1) * 4);
    int* wcur   = (int*)alloc((size_t)NN * 4);
    int* srcp   = (int*)alloc((size_t)EE * 4);
    int* gptr   = (int*)alloc((size_t)(GG + 1) * 4);
    int* bsum   = (int*)alloc((size_t)64 * 4);

    // ---- CSR build + ea permute (recomputed every call; deterministic work) ----
    hipMemsetAsync(cnt, 0, NN * sizeof(int), stream);
    hist_k<<<ceil_div(EE, 256), 256, 0, stream>>>(ei, cnt);
    const int NB = ceil_div(NN, 1024);
    scan1_k<<<NB, 1024, 0, stream>>>(cnt, NN, rowptr, bsum);
    scan2_k<<<1, 64, 0, stream>>>(bsum, NB);
    scan3_k<<<NB, 1024, 0, stream>>>(rowptr, wcur, bsum, NN);
    scatter_k<<<ceil_div(EE, 256), 256, 0, stream>>>(ei, (const float4*)ea, wcur, srcp, eaS);

    cvt_h<<<ceil_div(NN * 64 / 4, 256), 256, 0, stream>>>(x, hh, NN * 64 / 4);
    boundaries_k<<<ceil_div(NN, 256), 256, 0, stream>>>(batch, gptr);

    auto layer = [&](int K, float* hout, int relu, int wb) {
        W4 w4 = {{ W(wb + 0), W(wb + 2), W(wb + 4), W(wb + 7) }};   // q,k,v,s
        shuffle_w<<<dim3((K / 16) * 8, 4), 64, 0, stream>>>(w4, K, wshuf);
        if (K == 64)
            gemm_mfma<64><<<ceil_div(NN, 64), 256, 0, stream>>>(
                hh, wshuf, W(wb + 1), W(wb + 3), W(wb + 5), W(wb + 8), q, kh, vh, sk);
        else
            gemm_mfma<128><<<ceil_div(NN, 64), 256, 0, stream>>>(
                hh, wshuf, W(wb + 1), W(wb + 3), W(wb + 5), W(wb + 8), q, kh, vh, sk);
        node_agg<<<ceil_div(NN, 4), 256, 0, stream>>>(
            rowptr, srcp, eaS, q, kh, vh, W(wb + 6), sk, hout, hh, relu);
    };

    layer(64,  h1, 1, 4);
    layer(128, h2, 1, 13);
    layer(128, h1, 0, 22);

    head_k<<<GG, 128, 0, stream>>>(h1, gptr, W(31), W(32), (float*)d_out);
}

// Round 5
// 509.100 us; speedup vs baseline: 1.0433x; 1.0433x over previous
//
#include <hip/hip_runtime.h>
#include <math.h>

#define NN 50000
#define EE 800000
#define GG 1000

typedef __attribute__((ext_vector_type(4))) _Float16 h4f;
typedef __attribute__((ext_vector_type(8))) _Float16 h8f;
typedef __attribute__((ext_vector_type(4))) float f32x4;

static inline int ceil_div(int a, int b) { return (a + b - 1) / b; }

union EU { int2 i; h4f h; };

// ---------------- counting-sort of edges by dst (packed 16B records) ----------------

__global__ __launch_bounds__(256) void hist_k(const int* __restrict__ ei, int* __restrict__ cnt)
{
    int e = blockIdx.x * 256 + threadIdx.x;
    if (e >= EE) return;
    atomicAdd(&cnt[ei[EE + e]], 1);
}

__global__ __launch_bounds__(1024) void scan1_k(const int* __restrict__ cnt, int n,
                                                int* __restrict__ rowptr, int* __restrict__ bsum)
{
    __shared__ int tmp[1024];
    const int tid = threadIdx.x;
    const int i = blockIdx.x * 1024 + tid;
    tmp[tid] = (i < n) ? cnt[i] : 0;
    __syncthreads();
    for (int off = 1; off < 1024; off <<= 1) {
        int t = (tid >= off) ? tmp[tid - off] : 0;
        __syncthreads();
        tmp[tid] += t;
        __syncthreads();
    }
    if (i < n) rowptr[i + 1] = tmp[tid];
    if (tid == 1023) bsum[blockIdx.x] = tmp[1023];
}

__global__ void scan2_k(int* __restrict__ bsum, int nb)
{
    if (threadIdx.x == 0) {
        int run = 0;
        for (int i = 0; i < nb; ++i) { int t = bsum[i]; bsum[i] = run; run += t; }
    }
}

__global__ __launch_bounds__(1024) void scan3_k(int* __restrict__ rowptr,
                                                int* __restrict__ wcur,
                                                const int* __restrict__ bsum, int n)
{
    int i = blockIdx.x * 1024 + threadIdx.x;
    if (i < n) {
        int v = rowptr[i + 1] + bsum[blockIdx.x];
        rowptr[i + 1] = v;
        if (i + 1 < n) wcur[i + 1] = v;
    }
    if (i == 0) { rowptr[0] = 0; wcur[0] = 0; }
}

__global__ __launch_bounds__(256) void scatter_k(const int* __restrict__ ei,
                                                 const float4* __restrict__ ea,
                                                 int* __restrict__ wcur,
                                                 int4* __restrict__ edges)
{
    int e = blockIdx.x * 256 + threadIdx.x;
    if (e >= EE) return;
    int dst = ei[EE + e];
    int pos = atomicAdd(&wcur[dst], 1);
    float4 a = ea[e];
    EU u; u.h = h4f{(_Float16)a.x, (_Float16)a.y, (_Float16)a.z, (_Float16)a.w};
    edges[pos] = make_int4(ei[e], u.i.x, u.i.y, 0);
}

// ---------------- f32 -> f16 convert ----------------

__global__ __launch_bounds__(256) void cvt_h(const float* __restrict__ in,
                                             _Float16* __restrict__ out, int n4)
{
    int i = blockIdx.x * 256 + threadIdx.x;
    if (i >= n4) return;
    float4 v = reinterpret_cast<const float4*>(in)[i];
    h4f h = {(_Float16)v.x, (_Float16)v.y, (_Float16)v.z, (_Float16)v.w};
    reinterpret_cast<h4f*>(out)[i] = h;
}

// ---------------- weight shuffle: all 12 matrices in one launch ----------------
// layer 0: K=64 (mats 0..3), layers 1,2: K=128 (mats 4..11)
struct W12 { const float* w[12]; };

__global__ __launch_bounds__(64) void shuffle_w12(W12 ws, _Float16* __restrict__ out)
{
    const int m = blockIdx.y;
    const int K = (m < 4) ? 64 : 128;
    const int nblk = (K / 16) * 8;
    if (blockIdx.x >= nblk) return;
    const int s = blockIdx.x >> 3, c16 = blockIdx.x & 7;
    const int lane = threadIdx.x;
    const float* __restrict__ w = ws.w[m];
    const int kbase = s * 16 + (lane >> 4) * 4;
    const int col = c16 * 16 + (lane & 15);
    h4f h;
#pragma unroll
    for (int j = 0; j < 4; ++j) h[j] = (_Float16)w[(size_t)(kbase + j) * 128 + col];
    size_t base = (m < 4) ? (size_t)m * 64 * 128
                          : (size_t)4 * 64 * 128 + (size_t)(m - 4) * 128 * 128;
    reinterpret_cast<h4f*>(out + base)[(size_t)blockIdx.x * 64 + lane] = h;
}

// ---------------- fused 4-matrix MFMA GEMM (LDS-staged, vector stores) ----------------
// q,k,v -> f16; sk -> f32
template<int K>
__global__ __launch_bounds__(256) void gemm_mfma(
    const _Float16* __restrict__ xh, const _Float16* __restrict__ wshuf,
    const float* __restrict__ bq, const float* __restrict__ bk,
    const float* __restrict__ bv, const float* __restrict__ bs,
    _Float16* __restrict__ qout, _Float16* __restrict__ kout,
    _Float16* __restrict__ vout, float* __restrict__ skout)
{
    constexpr int KS = K / 16;
    constexpr int PADK = K + 8;
    __shared__ _Float16 xs[64 * PADK];
    const int t = threadIdx.x;
    const int bn = blockIdx.x * 64;
    constexpr int CH = K / 8;
    for (int idx = t; idx < 64 * CH; idx += 256) {
        const int row = idx / CH, ch = idx % CH;
        h8f val = {0, 0, 0, 0, 0, 0, 0, 0};
        if (bn + row < NN)
            val = reinterpret_cast<const h8f*>(xh + (size_t)(bn + row) * K)[ch];
        *reinterpret_cast<h8f*>(&xs[row * PADK + ch * 8]) = val;
    }
    __syncthreads();

    const int wid = t >> 6, lane = t & 63;
    const int rloc = wid * 16 + (lane & 15);
    const int ko = (lane >> 4) * 4;
    h4f b[KS];
#pragma unroll
    for (int s = 0; s < KS; ++s)
        b[s] = *reinterpret_cast<const h4f*>(&xs[rloc * PADK + s * 16 + ko]);

    const int node = bn + rloc;
    const int hcq = (lane >> 4) * 4;
    const float* bias[4] = {bq, bk, bv, bs};

#pragma unroll
    for (int m = 0; m < 4; ++m) {
        const h4f* __restrict__ wm = reinterpret_cast<const h4f*>(wshuf + (size_t)m * K * 128);
        f32x4 acc[8];
#pragma unroll
        for (int c = 0; c < 8; ++c) acc[c] = {0, 0, 0, 0};
#pragma unroll
        for (int c = 0; c < 8; ++c)
#pragma unroll
            for (int s = 0; s < KS; ++s) {
                h4f af = wm[(s * 8 + c) * 64 + lane];
                acc[c] = __builtin_amdgcn_mfma_f32_16x16x16f16(af, b[s], acc[c], 0, 0, 0);
            }
        if (node < NN) {
            const float* bm = bias[m];
#pragma unroll
            for (int c = 0; c < 8; ++c) {
                const int hc = c * 16 + hcq;
                const float4 bb = *reinterpret_cast<const float4*>(&bm[hc]);
                float o0 = acc[c][0] + bb.x, o1 = acc[c][1] + bb.y;
                float o2 = acc[c][2] + bb.z, o3 = acc[c][3] + bb.w;
                if (m == 3) {
                    *reinterpret_cast<float4*>(&skout[(size_t)node * 128 + hc]) =
                        make_float4(o0, o1, o2, o3);
                } else {
                    _Float16* dst = (m == 0) ? qout : (m == 1) ? kout : vout;
                    h4f oh = {(_Float16)o0, (_Float16)o1, (_Float16)o2, (_Float16)o3};
                    *reinterpret_cast<h4f*>(&dst[(size_t)node * 128 + hc]) = oh;
                }
            }
        }
    }
}

// ---------------- fused per-node attention aggregation ----------------
// 32-lane group per node, 4 channels/lane. eproj eliminated via
//   q.e = ea . (we_h @ q)   (qe precomputed per node)
//   sum(a~ * e) = we @ T,   T_h[d] = sum(a~ * ea[d])  (online-rescaled)
__global__ __launch_bounds__(256) void node_agg(
    const int* __restrict__ rowptr, const int4* __restrict__ edges,
    const _Float16* __restrict__ qh, const _Float16* __restrict__ kh,
    const _Float16* __restrict__ vh, const float* __restrict__ we,
    const float* __restrict__ sk, _Float16* __restrict__ houth, int relu)
{
    __shared__ float4 we_s[128];   // we [4][128] as float4[4][32]
    const int t = threadIdx.x;
    if (t < 128) we_s[t] = reinterpret_cast<const float4*>(we)[t];
    __syncthreads();
    const int node = blockIdx.x * 8 + (t >> 5);
    if (node >= NN) return;
    const int lane = t & 31;
    const int beg = rowptr[node], end = rowptr[node + 1];

    const float4 w0 = we_s[lane], w1 = we_s[32 + lane], w2 = we_s[64 + lane], w3 = we_s[96 + lane];

    // scaled q (scale folded once into q -> propagates to qk and qe)
    const h4f qv = *reinterpret_cast<const h4f*>(&qh[(size_t)node * 128 + lane * 4]);
    const float sc = 0.17677669529663687f;   // 1/sqrt(32)
    const float4 qf = make_float4((float)qv[0] * sc, (float)qv[1] * sc,
                                  (float)qv[2] * sc, (float)qv[3] * sc);

    // qe_h[d] = sum_{c in head} we[d][c] * qf[c]  (reduce over the 8-lane head group)
    float p0 = w0.x * qf.x + w0.y * qf.y + w0.z * qf.z + w0.w * qf.w;
    float p1 = w1.x * qf.x + w1.y * qf.y + w1.z * qf.z + w1.w * qf.w;
    float p2 = w2.x * qf.x + w2.y * qf.y + w2.z * qf.z + w2.w * qf.w;
    float p3 = w3.x * qf.x + w3.y * qf.y + w3.z * qf.z + w3.w * qf.w;
#pragma unroll
    for (int off = 1; off < 8; off <<= 1) {
        p0 += __shfl_xor(p0, off); p1 += __shfl_xor(p1, off);
        p2 += __shfl_xor(p2, off); p3 += __shfl_xor(p3, off);
    }
    const float qe0 = p0, qe1 = p1, qe2 = p2, qe3 = p3;

    float m = -INFINITY, s = 0.f;
    float4 acc = make_float4(0.f, 0.f, 0.f, 0.f);
    float T0 = 0.f, T1 = 0.f, T2 = 0.f, T3 = 0.f;

    int p = beg;
    for (; p + 1 < end; p += 2) {
        const int4 rA = edges[p], rB = edges[p + 1];
        EU uA, uB; uA.i = make_int2(rA.y, rA.z); uB.i = make_int2(rB.y, rB.z);
        const h4f eaA = uA.h, eaB = uB.h;
        const h4f kA = *reinterpret_cast<const h4f*>(&kh[(size_t)rA.x * 128 + lane * 4]);
        const h4f kB = *reinterpret_cast<const h4f*>(&kh[(size_t)rB.x * 128 + lane * 4]);
        const h4f vA = *reinterpret_cast<const h4f*>(&vh[(size_t)rA.x * 128 + lane * 4]);
        const h4f vB = *reinterpret_cast<const h4f*>(&vh[(size_t)rB.x * 128 + lane * 4]);
        float alA = qf.x * (float)kA[0] + qf.y * (float)kA[1]
                  + qf.z * (float)kA[2] + qf.w * (float)kA[3];
        float alB = qf.x * (float)kB[0] + qf.y * (float)kB[1]
                  + qf.z * (float)kB[2] + qf.w * (float)kB[3];
        alA += __shfl_xor(alA, 1); alA += __shfl_xor(alA, 2); alA += __shfl_xor(alA, 4);
        alB += __shfl_xor(alB, 1); alB += __shfl_xor(alB, 2); alB += __shfl_xor(alB, 4);
        const float fA0 = (float)eaA[0], fA1 = (float)eaA[1],
                    fA2 = (float)eaA[2], fA3 = (float)eaA[3];
        const float fB0 = (float)eaB[0], fB1 = (float)eaB[1],
                    fB2 = (float)eaB[2], fB3 = (float)eaB[3];
        alA += fA0 * qe0 + fA1 * qe1 + fA2 * qe2 + fA3 * qe3;
        alB += fB0 * qe0 + fB1 * qe1 + fB2 * qe2 + fB3 * qe3;
        const float mn = fmaxf(m, fmaxf(alA, alB));
        const float r  = __expf(m - mn);
        const float pA = __expf(alA - mn), pB = __expf(alB - mn);
        s = s * r + pA + pB;
        acc.x = acc.x * r + pA * (float)vA[0] + pB * (float)vB[0];
        acc.y = acc.y * r + pA * (float)vA[1] + pB * (float)vB[1];
        acc.z = acc.z * r + pA * (float)vA[2] + pB * (float)vB[2];
        acc.w = acc.w * r + pA * (float)vA[3] + pB * (float)vB[3];
        T0 = T0 * r + pA * fA0 + pB * fB0;
        T1 = T1 * r + pA * fA1 + pB * fB1;
        T2 = T2 * r + pA * fA2 + pB * fB2;
        T3 = T3 * r + pA * fA3 + pB * fB3;
        m = mn;
    }
    if (p < end) {
        const int4 rA = edges[p];
        EU uA; uA.i = make_int2(rA.y, rA.z);
        const h4f eaA = uA.h;
        const h4f kA = *reinterpret_cast<const h4f*>(&kh[(size_t)rA.x * 128 + lane * 4]);
        const h4f vA = *reinterpret_cast<const h4f*>(&vh[(size_t)rA.x * 128 + lane * 4]);
        float alA = qf.x * (float)kA[0] + qf.y * (float)kA[1]
                  + qf.z * (float)kA[2] + qf.w * (float)kA[3];
        alA += __shfl_xor(alA, 1); alA += __shfl_xor(alA, 2); alA += __shfl_xor(alA, 4);
        const float fA0 = (float)eaA[0], fA1 = (float)eaA[1],
                    fA2 = (float)eaA[2], fA3 = (float)eaA[3];
        alA += fA0 * qe0 + fA1 * qe1 + fA2 * qe2 + fA3 * qe3;
        const float mn = fmaxf(m, alA);
        const float r  = __expf(m - mn);
        const float pA = __expf(alA - mn);
        s = s * r + pA;
        acc.x = acc.x * r + pA * (float)vA[0];
        acc.y = acc.y * r + pA * (float)vA[1];
        acc.z = acc.z * r + pA * (float)vA[2];
        acc.w = acc.w * r + pA * (float)vA[3];
        T0 = T0 * r + pA * fA0;
        T1 = T1 * r + pA * fA1;
        T2 = T2 * r + pA * fA2;
        T3 = T3 * r + pA * fA3;
        m = mn;
    }
    const float inv = 1.0f / (s + 1e-16f);
    const float4 sk4 = *reinterpret_cast<const float4*>(&sk[(size_t)node * 128 + lane * 4]);
    float o0 = (acc.x + w0.x * T0 + w1.x * T1 + w2.x * T2 + w3.x * T3) * inv + sk4.x;
    float o1 = (acc.y + w0.y * T0 + w1.y * T1 + w2.y * T2 + w3.y * T3) * inv + sk4.y;
    float o2 = (acc.z + w0.z * T0 + w1.z * T1 + w2.z * T2 + w3.z * T3) * inv + sk4.z;
    float o3 = (acc.w + w0.w * T0 + w1.w * T1 + w2.w * T2 + w3.w * T3) * inv + sk4.w;
    if (relu) {
        o0 = fmaxf(o0, 0.f); o1 = fmaxf(o1, 0.f);
        o2 = fmaxf(o2, 0.f); o3 = fmaxf(o3, 0.f);
    }
    h4f oh = {(_Float16)o0, (_Float16)o1, (_Float16)o2, (_Float16)o3};
    *reinterpret_cast<h4f*>(&houth[(size_t)node * 128 + lane * 4]) = oh;
}

// ---------------- pooling + head (batch is sorted; h in f16) ----------------

__global__ __launch_bounds__(256) void boundaries_k(const int* __restrict__ batch,
                                                    int* __restrict__ gptr)
{
    int i = blockIdx.x * 256 + threadIdx.x;
    if (i >= NN) return;
    int b = batch[i];
    int bp = (i == 0) ? -1 : batch[i - 1];
    for (int g = bp + 1; g <= b; ++g) gptr[g] = i;
    if (i == NN - 1) for (int g = b + 1; g <= GG; ++g) gptr[g] = NN;
}

__global__ __launch_bounds__(128) void head_k(
    const _Float16* __restrict__ h, const int* __restrict__ gptr,
    const float* __restrict__ wlin, const float* __restrict__ blin,
    float* __restrict__ out)
{
    __shared__ float red[128];
    const int g = blockIdx.x;
    const int t = threadIdx.x;
    const int beg = gptr[g], end = gptr[g + 1];
    float p = 0.f;
    for (int n = beg; n < end; ++n) p += (float)h[(size_t)n * 128 + t];
    p *= wlin[t];
    red[t] = p;
    __syncthreads();
    for (int off = 64; off; off >>= 1) {
        if (t < off) red[t] += red[t + off];
        __syncthreads();
    }
    if (t == 0) out[g] = red[0] / fmaxf((float)(end - beg), 1.0f) + blin[0];
}

extern "C" void kernel_launch(void* const* d_in, const int* in_sizes, int n_in,
                              void* d_out, int out_size, void* d_ws, size_t ws_size,
                              hipStream_t stream)
{
    const float* x     = (const float*)d_in[0];
    const int*   ei    = (const int*)d_in[1];
    const float* ea    = (const float*)d_in[2];
    const int*   batch = (const int*)d_in[3];
    auto W = [&](int i) { return (const float*)d_in[i]; };

    char* wsb = (char*)d_ws;
    size_t off = 0;
    auto alloc = [&](size_t bytes) { void* p = wsb + off; off += (bytes + 15) & ~15ull; return p; };

    float* sk       = (float*)alloc((size_t)NN * 128 * 4);
    int4*  edges    = (int4*)alloc((size_t)EE * 16);
    _Float16* qh    = (_Float16*)alloc((size_t)NN * 128 * 2);
    _Float16* kh    = (_Float16*)alloc((size_t)NN * 128 * 2);
    _Float16* vh    = (_Float16*)alloc((size_t)NN * 128 * 2);
    _Float16* hh    = (_Float16*)alloc((size_t)NN * 128 * 2);
    _Float16* wshuf = (_Float16*)alloc(((size_t)4 * 64 * 128 + 8 * 128 * 128) * 2);
    int* cnt    = (int*)alloc((size_t)NN * 4);
    int* rowptr = (int*)alloc((size_t)(NN + 1) * 4);
    int* wcur   = (int*)alloc((size_t)NN * 4);
    int* gptr   = (int*)alloc((size_t)(GG + 1) * 4);
    int* bsum   = (int*)alloc((size_t)64 * 4);

    // ---- CSR build + packed edge records (recomputed each call; deterministic work) ----
    hipMemsetAsync(cnt, 0, NN * sizeof(int), stream);
    hist_k<<<ceil_div(EE, 256), 256, 0, stream>>>(ei, cnt);
    const int NB = ceil_div(NN, 1024);
    scan1_k<<<NB, 1024, 0, stream>>>(cnt, NN, rowptr, bsum);
    scan2_k<<<1, 64, 0, stream>>>(bsum, NB);
    scan3_k<<<NB, 1024, 0, stream>>>(rowptr, wcur, bsum, NN);
    scatter_k<<<ceil_div(EE, 256), 256, 0, stream>>>(ei, (const float4*)ea, wcur, edges);

    cvt_h<<<ceil_div(NN * 64 / 4, 256), 256, 0, stream>>>(x, hh, NN * 64 / 4);
    boundaries_k<<<ceil_div(NN, 256), 256, 0, stream>>>(batch, gptr);

    // all 12 weight matrices shuffled in one launch
    W12 w12 = {{ W(4), W(6), W(8), W(11),          // layer1 q,k,v,s (K=64)
                 W(13), W(15), W(17), W(20),       // layer2 (K=128)
                 W(22), W(24), W(26), W(29) }};    // layer3 (K=128)
    shuffle_w12<<<dim3(64, 12), 64, 0, stream>>>(w12, wshuf);
    const size_t wsz1 = (size_t)4 * 64 * 128;
    const size_t wsz2 = (size_t)4 * 128 * 128;

    auto layer = [&](int K, const _Float16* wsh, int relu, int wb) {
        if (K == 64)
            gemm_mfma<64><<<ceil_div(NN, 64), 256, 0, stream>>>(
                hh, wsh, W(wb + 1), W(wb + 3), W(wb + 5), W(wb + 8), qh, kh, vh, sk);
        else
            gemm_mfma<128><<<ceil_div(NN, 64), 256, 0, stream>>>(
                hh, wsh, W(wb + 1), W(wb + 3), W(wb + 5), W(wb + 8), qh, kh, vh, sk);
        node_agg<<<ceil_div(NN, 8), 256, 0, stream>>>(
            rowptr, edges, qh, kh, vh, W(wb + 6), sk, hh, relu);
    };

    layer(64,  wshuf, 1, 4);
    layer(128, wshuf + wsz1, 1, 13);
    layer(128, wshuf + wsz1 + wsz2, 0, 22);

    head_k<<<GG, 128, 0, stream>>>(hh, gptr, W(31), W(32), (float*)d_out);
}

// Round 6
// 495.022 us; speedup vs baseline: 1.0730x; 1.0284x over previous
//
#include <hip/hip_runtime.h>
#include <math.h>

#define NN 50000
#define EE 800000
#define GG 1000

typedef __attribute__((ext_vector_type(4))) _Float16 h4f;
typedef __attribute__((ext_vector_type(8))) _Float16 h8f;
typedef __attribute__((ext_vector_type(4))) float f32x4;

static inline int ceil_div(int a, int b) { return (a + b - 1) / b; }

union EU { int2 i; h4f h; };

// ---------------- counting-sort of edges by dst (packed 16B records) ----------------

__global__ __launch_bounds__(256) void hist_k(const int* __restrict__ ei, int* __restrict__ cnt)
{
    int e = blockIdx.x * 256 + threadIdx.x;
    if (e >= EE) return;
    atomicAdd(&cnt[ei[EE + e]], 1);
}

__global__ __launch_bounds__(1024) void scan1_k(const int* __restrict__ cnt, int n,
                                                int* __restrict__ rowptr, int* __restrict__ bsum)
{
    __shared__ int tmp[1024];
    const int tid = threadIdx.x;
    const int i = blockIdx.x * 1024 + tid;
    tmp[tid] = (i < n) ? cnt[i] : 0;
    __syncthreads();
    for (int off = 1; off < 1024; off <<= 1) {
        int t = (tid >= off) ? tmp[tid - off] : 0;
        __syncthreads();
        tmp[tid] += t;
        __syncthreads();
    }
    if (i < n) rowptr[i + 1] = tmp[tid];
    if (tid == 1023) bsum[blockIdx.x] = tmp[1023];
}

__global__ __launch_bounds__(64) void scan2_k(int* __restrict__ bsum, int nb)
{
    const int t = threadIdx.x;
    int v = (t < nb) ? bsum[t] : 0;
    const int orig = v;
    for (int off = 1; off < 64; off <<= 1) {
        int n = __shfl_up(v, off);
        if (t >= off) v += n;
    }
    if (t < nb) bsum[t] = v - orig;   // exclusive prefix
}

__global__ __launch_bounds__(1024) void scan3_k(int* __restrict__ rowptr,
                                                int* __restrict__ wcur,
                                                const int* __restrict__ bsum, int n)
{
    int i = blockIdx.x * 1024 + threadIdx.x;
    if (i < n) {
        int v = rowptr[i + 1] + bsum[blockIdx.x];
        rowptr[i + 1] = v;
        if (i + 1 < n) wcur[i + 1] = v;
    }
    if (i == 0) { rowptr[0] = 0; wcur[0] = 0; }
}

__global__ __launch_bounds__(256) void scatter_k(const int* __restrict__ ei,
                                                 const float4* __restrict__ ea,
                                                 int* __restrict__ wcur,
                                                 int4* __restrict__ edges)
{
    int e = blockIdx.x * 256 + threadIdx.x;
    if (e >= EE) return;
    int dst = ei[EE + e];
    int pos = atomicAdd(&wcur[dst], 1);
    float4 a = ea[e];
    EU u; u.h = h4f{(_Float16)a.x, (_Float16)a.y, (_Float16)a.z, (_Float16)a.w};
    edges[pos] = make_int4(ei[e], u.i.x, u.i.y, 0);
}

// ---------------- weight shuffle: all 12 matrices in one launch ----------------
struct W12 { const float* w[12]; };

__global__ __launch_bounds__(64) void shuffle_w12(W12 ws, _Float16* __restrict__ out)
{
    const int m = blockIdx.y;
    const int K = (m < 4) ? 64 : 128;
    const int nblk = (K / 16) * 8;
    if (blockIdx.x >= nblk) return;
    const int s = blockIdx.x >> 3, c16 = blockIdx.x & 7;
    const int lane = threadIdx.x;
    const float* __restrict__ w = ws.w[m];
    const int kbase = s * 16 + (lane >> 4) * 4;
    const int col = c16 * 16 + (lane & 15);
    h4f h;
#pragma unroll
    for (int j = 0; j < 4; ++j) h[j] = (_Float16)w[(size_t)(kbase + j) * 128 + col];
    size_t base = (m < 4) ? (size_t)m * 64 * 128
                          : (size_t)4 * 64 * 128 + (size_t)(m - 4) * 128 * 128;
    reinterpret_cast<h4f*>(out + base)[(size_t)blockIdx.x * 64 + lane] = h;
}

// ---------------- fused 4-matrix MFMA GEMM (LDS x-tile + LDS weight tile) ----------------
// q,k,v -> f16; sk -> f32.  F32IN: stage+convert f32 input (layer 1).
template<int K, bool F32IN>
__global__ __launch_bounds__(256) void gemm_mfma(
    const void* __restrict__ xin, const _Float16* __restrict__ wshuf,
    const float* __restrict__ bq, const float* __restrict__ bk,
    const float* __restrict__ bv, const float* __restrict__ bs,
    _Float16* __restrict__ qout, _Float16* __restrict__ kout,
    _Float16* __restrict__ vout, float* __restrict__ skout)
{
    constexpr int KS = K / 16;
    constexpr int PADK = K + 8;
    __shared__ _Float16 xs[64 * PADK];
    __shared__ _Float16 wt[K * 128];
    const int t = threadIdx.x;
    const int bn = blockIdx.x * 64;
    if (F32IN) {
        const float* xf = (const float*)xin;
        constexpr int C4 = K / 4;
        for (int idx = t; idx < 64 * C4; idx += 256) {
            const int row = idx / C4, c4 = idx % C4;
            float4 val = make_float4(0.f, 0.f, 0.f, 0.f);
            if (bn + row < NN)
                val = reinterpret_cast<const float4*>(xf)[(size_t)(bn + row) * C4 + c4];
            h4f h = {(_Float16)val.x, (_Float16)val.y, (_Float16)val.z, (_Float16)val.w};
            *reinterpret_cast<h4f*>(&xs[row * PADK + c4 * 4]) = h;
        }
    } else {
        const _Float16* xh = (const _Float16*)xin;
        constexpr int CH = K / 8;
        for (int idx = t; idx < 64 * CH; idx += 256) {
            const int row = idx / CH, ch = idx % CH;
            h8f val = {0, 0, 0, 0, 0, 0, 0, 0};
            if (bn + row < NN)
                val = reinterpret_cast<const h8f*>(xh + (size_t)(bn + row) * K)[ch];
            *reinterpret_cast<h8f*>(&xs[row * PADK + ch * 8]) = val;
        }
    }
    __syncthreads();

    const int wid = t >> 6, lane = t & 63;
    const int rloc = wid * 16 + (lane & 15);
    const int ko = (lane >> 4) * 4;
    h4f b[KS];
#pragma unroll
    for (int s = 0; s < KS; ++s)
        b[s] = *reinterpret_cast<const h4f*>(&xs[rloc * PADK + s * 16 + ko]);

    const int node = bn + rloc;
    const int hcq = (lane >> 4) * 4;
    const float* bias[4] = {bq, bk, bv, bs};
    constexpr int WH4 = K * 128 / 4;   // h4f elements per matrix

#pragma unroll
    for (int m = 0; m < 4; ++m) {
        // stage weight matrix m into LDS (coalesced, shared across 4 waves)
        const h4f* __restrict__ wg = reinterpret_cast<const h4f*>(wshuf + (size_t)m * K * 128);
        h4f* __restrict__ wl = reinterpret_cast<h4f*>(wt);
        for (int idx = t; idx < WH4; idx += 256) wl[idx] = wg[idx];
        __syncthreads();

        f32x4 acc[8];
#pragma unroll
        for (int c = 0; c < 8; ++c) acc[c] = {0, 0, 0, 0};
#pragma unroll
        for (int c = 0; c < 8; ++c)
#pragma unroll
            for (int s = 0; s < KS; ++s) {
                h4f af = wl[(s * 8 + c) * 64 + lane];
                acc[c] = __builtin_amdgcn_mfma_f32_16x16x16f16(af, b[s], acc[c], 0, 0, 0);
            }
        if (node < NN) {
            const float* bm = bias[m];
#pragma unroll
            for (int c = 0; c < 8; ++c) {
                const int hc = c * 16 + hcq;
                const float4 bb = *reinterpret_cast<const float4*>(&bm[hc]);
                float o0 = acc[c][0] + bb.x, o1 = acc[c][1] + bb.y;
                float o2 = acc[c][2] + bb.z, o3 = acc[c][3] + bb.w;
                if (m == 3) {
                    *reinterpret_cast<float4*>(&skout[(size_t)node * 128 + hc]) =
                        make_float4(o0, o1, o2, o3);
                } else {
                    _Float16* dst = (m == 0) ? qout : (m == 1) ? kout : vout;
                    h4f oh = {(_Float16)o0, (_Float16)o1, (_Float16)o2, (_Float16)o3};
                    *reinterpret_cast<h4f*>(&dst[(size_t)node * 128 + hc]) = oh;
                }
            }
        }
        __syncthreads();   // protect wt before next stage
    }
}

// ---------------- fused per-node attention aggregation ----------------
// 32-lane group per node, 4 channels/lane, 4-edge unrolled online softmax (exp2 domain).
//   q.e = ea . (we_h @ q)  precomputed;  sum(a~*e) = we @ T (T online-rescaled)
__global__ __launch_bounds__(256) void node_agg(
    const int* __restrict__ rowptr, const int4* __restrict__ edges,
    const _Float16* __restrict__ qh, const _Float16* __restrict__ kh,
    const _Float16* __restrict__ vh, const float* __restrict__ we,
    const float* __restrict__ sk, _Float16* __restrict__ houth, int relu)
{
    __shared__ float4 we_s[128];
    const int t = threadIdx.x;
    if (t < 128) we_s[t] = reinterpret_cast<const float4*>(we)[t];
    __syncthreads();
    const int node = blockIdx.x * 8 + (t >> 5);
    if (node >= NN) return;
    const int lane = t & 31;
    const int beg = rowptr[node], end = rowptr[node + 1];

    const float4 w0 = we_s[lane], w1 = we_s[32 + lane], w2 = we_s[64 + lane], w3 = we_s[96 + lane];

    // q scaled by (1/sqrt(32))*log2(e): exp(x) -> exp2 domain, exact reassociation
    const h4f qv = *reinterpret_cast<const h4f*>(&qh[(size_t)node * 128 + lane * 4]);
    const float sc = 0.17677669529663687f * 1.4426950408889634f;
    const float4 qf = make_float4((float)qv[0] * sc, (float)qv[1] * sc,
                                  (float)qv[2] * sc, (float)qv[3] * sc);

    float p0 = w0.x * qf.x + w0.y * qf.y + w0.z * qf.z + w0.w * qf.w;
    float p1 = w1.x * qf.x + w1.y * qf.y + w1.z * qf.z + w1.w * qf.w;
    float p2 = w2.x * qf.x + w2.y * qf.y + w2.z * qf.z + w2.w * qf.w;
    float p3 = w3.x * qf.x + w3.y * qf.y + w3.z * qf.z + w3.w * qf.w;
#pragma unroll
    for (int off = 1; off < 8; off <<= 1) {
        p0 += __shfl_xor(p0, off); p1 += __shfl_xor(p1, off);
        p2 += __shfl_xor(p2, off); p3 += __shfl_xor(p3, off);
    }
    const float qe0 = p0, qe1 = p1, qe2 = p2, qe3 = p3;

    float m = -INFINITY, s = 0.f;
    float4 acc = make_float4(0.f, 0.f, 0.f, 0.f);
    float T0 = 0.f, T1 = 0.f, T2 = 0.f, T3 = 0.f;

    int p = beg;
    for (; p + 3 < end; p += 4) {
        const int4 rA = edges[p], rB = edges[p + 1], rC = edges[p + 2], rD = edges[p + 3];
        EU uA, uB, uC, uD;
        uA.i = make_int2(rA.y, rA.z); uB.i = make_int2(rB.y, rB.z);
        uC.i = make_int2(rC.y, rC.z); uD.i = make_int2(rD.y, rD.z);
        const h4f kA = *reinterpret_cast<const h4f*>(&kh[(size_t)rA.x * 128 + lane * 4]);
        const h4f kB = *reinterpret_cast<const h4f*>(&kh[(size_t)rB.x * 128 + lane * 4]);
        const h4f kC = *reinterpret_cast<const h4f*>(&kh[(size_t)rC.x * 128 + lane * 4]);
        const h4f kD = *reinterpret_cast<const h4f*>(&kh[(size_t)rD.x * 128 + lane * 4]);
        const h4f vA = *reinterpret_cast<const h4f*>(&vh[(size_t)rA.x * 128 + lane * 4]);
        const h4f vB = *reinterpret_cast<const h4f*>(&vh[(size_t)rB.x * 128 + lane * 4]);
        const h4f vC = *reinterpret_cast<const h4f*>(&vh[(size_t)rC.x * 128 + lane * 4]);
        const h4f vD = *reinterpret_cast<const h4f*>(&vh[(size_t)rD.x * 128 + lane * 4]);
        float alA = qf.x * (float)kA[0] + qf.y * (float)kA[1]
                  + qf.z * (float)kA[2] + qf.w * (float)kA[3];
        float alB = qf.x * (float)kB[0] + qf.y * (float)kB[1]
                  + qf.z * (float)kB[2] + qf.w * (float)kB[3];
        float alC = qf.x * (float)kC[0] + qf.y * (float)kC[1]
                  + qf.z * (float)kC[2] + qf.w * (float)kC[3];
        float alD = qf.x * (float)kD[0] + qf.y * (float)kD[1]
                  + qf.z * (float)kD[2] + qf.w * (float)kD[3];
        alA += __shfl_xor(alA, 1); alA += __shfl_xor(alA, 2); alA += __shfl_xor(alA, 4);
        alB += __shfl_xor(alB, 1); alB += __shfl_xor(alB, 2); alB += __shfl_xor(alB, 4);
        alC += __shfl_xor(alC, 1); alC += __shfl_xor(alC, 2); alC += __shfl_xor(alC, 4);
        alD += __shfl_xor(alD, 1); alD += __shfl_xor(alD, 2); alD += __shfl_xor(alD, 4);
        const float fA0 = (float)uA.h[0], fA1 = (float)uA.h[1],
                    fA2 = (float)uA.h[2], fA3 = (float)uA.h[3];
        const float fB0 = (float)uB.h[0], fB1 = (float)uB.h[1],
                    fB2 = (float)uB.h[2], fB3 = (float)uB.h[3];
        const float fC0 = (float)uC.h[0], fC1 = (float)uC.h[1],
                    fC2 = (float)uC.h[2], fC3 = (float)uC.h[3];
        const float fD0 = (float)uD.h[0], fD1 = (float)uD.h[1],
                    fD2 = (float)uD.h[2], fD3 = (float)uD.h[3];
        alA += fA0 * qe0 + fA1 * qe1 + fA2 * qe2 + fA3 * qe3;
        alB += fB0 * qe0 + fB1 * qe1 + fB2 * qe2 + fB3 * qe3;
        alC += fC0 * qe0 + fC1 * qe1 + fC2 * qe2 + fC3 * qe3;
        alD += fD0 * qe0 + fD1 * qe1 + fD2 * qe2 + fD3 * qe3;
        const float mn = fmaxf(fmaxf(fmaxf(alA, alB), fmaxf(alC, alD)), m);
        const float r  = exp2f(m - mn);
        const float pA = exp2f(alA - mn), pB = exp2f(alB - mn);
        const float pC = exp2f(alC - mn), pD = exp2f(alD - mn);
        s = s * r + pA + pB + pC + pD;
        acc.x = acc.x * r + pA * (float)vA[0] + pB * (float)vB[0]
                          + pC * (float)vC[0] + pD * (float)vD[0];
        acc.y = acc.y * r + pA * (float)vA[1] + pB * (float)vB[1]
                          + pC * (float)vC[1] + pD * (float)vD[1];
        acc.z = acc.z * r + pA * (float)vA[2] + pB * (float)vB[2]
                          + pC * (float)vC[2] + pD * (float)vD[2];
        acc.w = acc.w * r + pA * (float)vA[3] + pB * (float)vB[3]
                          + pC * (float)vC[3] + pD * (float)vD[3];
        T0 = T0 * r + pA * fA0 + pB * fB0 + pC * fC0 + pD * fD0;
        T1 = T1 * r + pA * fA1 + pB * fB1 + pC * fC1 + pD * fD1;
        T2 = T2 * r + pA * fA2 + pB * fB2 + pC * fC2 + pD * fD2;
        T3 = T3 * r + pA * fA3 + pB * fB3 + pC * fC3 + pD * fD3;
        m = mn;
    }
    for (; p < end; ++p) {
        const int4 rA = edges[p];
        EU uA; uA.i = make_int2(rA.y, rA.z);
        const h4f kA = *reinterpret_cast<const h4f*>(&kh[(size_t)rA.x * 128 + lane * 4]);
        const h4f vA = *reinterpret_cast<const h4f*>(&vh[(size_t)rA.x * 128 + lane * 4]);
        float alA = qf.x * (float)kA[0] + qf.y * (float)kA[1]
                  + qf.z * (float)kA[2] + qf.w * (float)kA[3];
        alA += __shfl_xor(alA, 1); alA += __shfl_xor(alA, 2); alA += __shfl_xor(alA, 4);
        const float fA0 = (float)uA.h[0], fA1 = (float)uA.h[1],
                    fA2 = (float)uA.h[2], fA3 = (float)uA.h[3];
        alA += fA0 * qe0 + fA1 * qe1 + fA2 * qe2 + fA3 * qe3;
        const float mn = fmaxf(m, alA);
        const float r  = exp2f(m - mn);
        const float pA = exp2f(alA - mn);
        s = s * r + pA;
        acc.x = acc.x * r + pA * (float)vA[0];
        acc.y = acc.y * r + pA * (float)vA[1];
        acc.z = acc.z * r + pA * (float)vA[2];
        acc.w = acc.w * r + pA * (float)vA[3];
        T0 = T0 * r + pA * fA0;
        T1 = T1 * r + pA * fA1;
        T2 = T2 * r + pA * fA2;
        T3 = T3 * r + pA * fA3;
        m = mn;
    }
    const float inv = 1.0f / (s + 1e-16f);
    const float4 sk4 = *reinterpret_cast<const float4*>(&sk[(size_t)node * 128 + lane * 4]);
    float o0 = (acc.x + w0.x * T0 + w1.x * T1 + w2.x * T2 + w3.x * T3) * inv + sk4.x;
    float o1 = (acc.y + w0.y * T0 + w1.y * T1 + w2.y * T2 + w3.y * T3) * inv + sk4.y;
    float o2 = (acc.z + w0.z * T0 + w1.z * T1 + w2.z * T2 + w3.z * T3) * inv + sk4.z;
    float o3 = (acc.w + w0.w * T0 + w1.w * T1 + w2.w * T2 + w3.w * T3) * inv + sk4.w;
    if (relu) {
        o0 = fmaxf(o0, 0.f); o1 = fmaxf(o1, 0.f);
        o2 = fmaxf(o2, 0.f); o3 = fmaxf(o3, 0.f);
    }
    h4f oh = {(_Float16)o0, (_Float16)o1, (_Float16)o2, (_Float16)o3};
    *reinterpret_cast<h4f*>(&houth[(size_t)node * 128 + lane * 4]) = oh;
}

// ---------------- pooling + head (batch is sorted; h in f16) ----------------

__global__ __launch_bounds__(256) void boundaries_k(const int* __restrict__ batch,
                                                    int* __restrict__ gptr)
{
    int i = blockIdx.x * 256 + threadIdx.x;
    if (i >= NN) return;
    int b = batch[i];
    int bp = (i == 0) ? -1 : batch[i - 1];
    for (int g = bp + 1; g <= b; ++g) gptr[g] = i;
    if (i == NN - 1) for (int g = b + 1; g <= GG; ++g) gptr[g] = NN;
}

__global__ __launch_bounds__(128) void head_k(
    const _Float16* __restrict__ h, const int* __restrict__ gptr,
    const float* __restrict__ wlin, const float* __restrict__ blin,
    float* __restrict__ out)
{
    __shared__ float red[128];
    const int g = blockIdx.x;
    const int t = threadIdx.x;
    const int beg = gptr[g], end = gptr[g + 1];
    float p = 0.f;
    for (int n = beg; n < end; ++n) p += (float)h[(size_t)n * 128 + t];
    p *= wlin[t];
    red[t] = p;
    __syncthreads();
    for (int off = 64; off; off >>= 1) {
        if (t < off) red[t] += red[t + off];
        __syncthreads();
    }
    if (t == 0) out[g] = red[0] / fmaxf((float)(end - beg), 1.0f) + blin[0];
}

extern "C" void kernel_launch(void* const* d_in, const int* in_sizes, int n_in,
                              void* d_out, int out_size, void* d_ws, size_t ws_size,
                              hipStream_t stream)
{
    const float* x     = (const float*)d_in[0];
    const int*   ei    = (const int*)d_in[1];
    const float* ea    = (const float*)d_in[2];
    const int*   batch = (const int*)d_in[3];
    auto W = [&](int i) { return (const float*)d_in[i]; };

    char* wsb = (char*)d_ws;
    size_t off = 0;
    auto alloc = [&](size_t bytes) { void* p = wsb + off; off += (bytes + 15) & ~15ull; return p; };

    float* sk       = (float*)alloc((size_t)NN * 128 * 4);
    int4*  edges    = (int4*)alloc((size_t)EE * 16);
    _Float16* qh    = (_Float16*)alloc((size_t)NN * 128 * 2);
    _Float16* kh    = (_Float16*)alloc((size_t)NN * 128 * 2);
    _Float16* vh    = (_Float16*)alloc((size_t)NN * 128 * 2);
    _Float16* hh    = (_Float16*)alloc((size_t)NN * 128 * 2);
    _Float16* wshuf = (_Float16*)alloc(((size_t)4 * 64 * 128 + 8 * 128 * 128) * 2);
    int* cnt    = (int*)alloc((size_t)NN * 4);
    int* rowptr = (int*)alloc((size_t)(NN + 1) * 4);
    int* wcur   = (int*)alloc((size_t)NN * 4);
    int* gptr   = (int*)alloc((size_t)(GG + 1) * 4);
    int* bsum   = (int*)alloc((size_t)64 * 4);

    // ---- CSR build + packed edge records (recomputed each call; deterministic) ----
    hipMemsetAsync(cnt, 0, NN * sizeof(int), stream);
    hist_k<<<ceil_div(EE, 256), 256, 0, stream>>>(ei, cnt);
    const int NB = ceil_div(NN, 1024);
    scan1_k<<<NB, 1024, 0, stream>>>(cnt, NN, rowptr, bsum);
    scan2_k<<<1, 64, 0, stream>>>(bsum, NB);
    scan3_k<<<NB, 1024, 0, stream>>>(rowptr, wcur, bsum, NN);
    scatter_k<<<ceil_div(EE, 256), 256, 0, stream>>>(ei, (const float4*)ea, wcur, edges);

    boundaries_k<<<ceil_div(NN, 256), 256, 0, stream>>>(batch, gptr);

    W12 w12 = {{ W(4), W(6), W(8), W(11),
                 W(13), W(15), W(17), W(20),
                 W(22), W(24), W(26), W(29) }};
    shuffle_w12<<<dim3(64, 12), 64, 0, stream>>>(w12, wshuf);
    const size_t wsz1 = (size_t)4 * 64 * 128;
    const size_t wsz2 = (size_t)4 * 128 * 128;

    auto layer = [&](int K, const void* xin, const _Float16* wsh, int relu, int wb) {
        if (K == 64)
            gemm_mfma<64, true><<<ceil_div(NN, 64), 256, 0, stream>>>(
                xin, wsh, W(wb + 1), W(wb + 3), W(wb + 5), W(wb + 8), qh, kh, vh, sk);
        else
            gemm_mfma<128, false><<<ceil_div(NN, 64), 256, 0, stream>>>(
                xin, wsh, W(wb + 1), W(wb + 3), W(wb + 5), W(wb + 8), qh, kh, vh, sk);
        node_agg<<<ceil_div(NN, 8), 256, 0, stream>>>(
            rowptr, edges, qh, kh, vh, W(wb + 6), sk, hh, relu);
    };

    layer(64,  x,  wshuf, 1, 4);
    layer(128, hh, wshuf + wsz1, 1, 13);
    layer(128, hh, wshuf + wsz1 + wsz2, 0, 22);

    head_k<<<GG, 128, 0, stream>>>(hh, gptr, W(31), W(32), (float*)d_out);
}

// Round 7
// 477.748 us; speedup vs baseline: 1.1118x; 1.0362x over previous
//
#include <hip/hip_runtime.h>
#include <math.h>

#define NN 50000
#define EE 800000
#define GG 1000

typedef __attribute__((ext_vector_type(4))) _Float16 h4f;
typedef __attribute__((ext_vector_type(8))) _Float16 h8f;
typedef __attribute__((ext_vector_type(4))) float f32x4;

static inline int ceil_div(int a, int b) { return (a + b - 1) / b; }

union EU { int2 i; h4f h; };

// ---------------- counting-sort of edges by dst (packed 16B records) ----------------

__global__ __launch_bounds__(256) void hist_k(const int* __restrict__ ei, int* __restrict__ cnt)
{
    int e = blockIdx.x * 256 + threadIdx.x;
    if (e >= EE) return;
    atomicAdd(&cnt[ei[EE + e]], 1);
}

__global__ __launch_bounds__(1024) void scan1_k(const int* __restrict__ cnt, int n,
                                                int* __restrict__ rowptr, int* __restrict__ bsum)
{
    __shared__ int tmp[1024];
    const int tid = threadIdx.x;
    const int i = blockIdx.x * 1024 + tid;
    tmp[tid] = (i < n) ? cnt[i] : 0;
    __syncthreads();
    for (int off = 1; off < 1024; off <<= 1) {
        int t = (tid >= off) ? tmp[tid - off] : 0;
        __syncthreads();
        tmp[tid] += t;
        __syncthreads();
    }
    if (i < n) rowptr[i + 1] = tmp[tid];
    if (tid == 1023) bsum[blockIdx.x] = tmp[1023];
}

__global__ __launch_bounds__(64) void scan2_k(int* __restrict__ bsum, int nb)
{
    const int t = threadIdx.x;
    int v = (t < nb) ? bsum[t] : 0;
    const int orig = v;
    for (int off = 1; off < 64; off <<= 1) {
        int n = __shfl_up(v, off);
        if (t >= off) v += n;
    }
    if (t < nb) bsum[t] = v - orig;   // exclusive prefix
}

__global__ __launch_bounds__(1024) void scan3_k(int* __restrict__ rowptr,
                                                int* __restrict__ wcur,
                                                const int* __restrict__ bsum, int n)
{
    int i = blockIdx.x * 1024 + threadIdx.x;
    if (i < n) {
        int v = rowptr[i + 1] + bsum[blockIdx.x];
        rowptr[i + 1] = v;
        if (i + 1 < n) wcur[i + 1] = v;
    }
    if (i == 0) { rowptr[0] = 0; wcur[0] = 0; }
}

__global__ __launch_bounds__(256) void scatter_k(const int* __restrict__ ei,
                                                 const float4* __restrict__ ea,
                                                 int* __restrict__ wcur,
                                                 int4* __restrict__ edges)
{
    int e = blockIdx.x * 256 + threadIdx.x;
    if (e >= EE) return;
    int dst = ei[EE + e];
    int pos = atomicAdd(&wcur[dst], 1);
    float4 a = ea[e];
    EU u; u.h = h4f{(_Float16)a.x, (_Float16)a.y, (_Float16)a.z, (_Float16)a.w};
    edges[pos] = make_int4(ei[e], u.i.x, u.i.y, 0);
}

// ---------------- weight shuffle: all 12 matrices in one launch ----------------
struct W12 { const float* w[12]; };

__global__ __launch_bounds__(64) void shuffle_w12(W12 ws, _Float16* __restrict__ out)
{
    const int m = blockIdx.y;
    const int K = (m < 4) ? 64 : 128;
    const int nblk = (K / 16) * 8;
    if (blockIdx.x >= nblk) return;
    const int s = blockIdx.x >> 3, c16 = blockIdx.x & 7;
    const int lane = threadIdx.x;
    const float* __restrict__ w = ws.w[m];
    const int kbase = s * 16 + (lane >> 4) * 4;
    const int col = c16 * 16 + (lane & 15);
    h4f h;
#pragma unroll
    for (int j = 0; j < 4; ++j) h[j] = (_Float16)w[(size_t)(kbase + j) * 128 + col];
    size_t base = (m < 4) ? (size_t)m * 64 * 128
                          : (size_t)4 * 64 * 128 + (size_t)(m - 4) * 128 * 128;
    reinterpret_cast<h4f*>(out + base)[(size_t)blockIdx.x * 64 + lane] = h;
}

// ---------------- fused 4-matrix MFMA GEMM (LDS x-tile + LDS weight tile) ----------------
template<int K, bool F32IN>
__global__ __launch_bounds__(256) void gemm_mfma(
    const void* __restrict__ xin, const _Float16* __restrict__ wshuf,
    const float* __restrict__ bq, const float* __restrict__ bk,
    const float* __restrict__ bv, const float* __restrict__ bs,
    _Float16* __restrict__ qout, _Float16* __restrict__ kout,
    _Float16* __restrict__ vout, float* __restrict__ skout)
{
    constexpr int KS = K / 16;
    constexpr int PADK = K + 8;
    __shared__ _Float16 xs[64 * PADK];
    __shared__ _Float16 wt[K * 128];
    const int t = threadIdx.x;
    const int bn = blockIdx.x * 64;
    if (F32IN) {
        const float* xf = (const float*)xin;
        constexpr int C4 = K / 4;
        for (int idx = t; idx < 64 * C4; idx += 256) {
            const int row = idx / C4, c4 = idx % C4;
            float4 val = make_float4(0.f, 0.f, 0.f, 0.f);
            if (bn + row < NN)
                val = reinterpret_cast<const float4*>(xf)[(size_t)(bn + row) * C4 + c4];
            h4f h = {(_Float16)val.x, (_Float16)val.y, (_Float16)val.z, (_Float16)val.w};
            *reinterpret_cast<h4f*>(&xs[row * PADK + c4 * 4]) = h;
        }
    } else {
        const _Float16* xh = (const _Float16*)xin;
        constexpr int CH = K / 8;
        for (int idx = t; idx < 64 * CH; idx += 256) {
            const int row = idx / CH, ch = idx % CH;
            h8f val = {0, 0, 0, 0, 0, 0, 0, 0};
            if (bn + row < NN)
                val = reinterpret_cast<const h8f*>(xh + (size_t)(bn + row) * K)[ch];
            *reinterpret_cast<h8f*>(&xs[row * PADK + ch * 8]) = val;
        }
    }
    __syncthreads();

    const int wid = t >> 6, lane = t & 63;
    const int rloc = wid * 16 + (lane & 15);
    const int ko = (lane >> 4) * 4;
    h4f b[KS];
#pragma unroll
    for (int s = 0; s < KS; ++s)
        b[s] = *reinterpret_cast<const h4f*>(&xs[rloc * PADK + s * 16 + ko]);

    const int node = bn + rloc;
    const int hcq = (lane >> 4) * 4;
    const float* bias[4] = {bq, bk, bv, bs};
    constexpr int WH4 = K * 128 / 4;

#pragma unroll
    for (int m = 0; m < 4; ++m) {
        const h4f* __restrict__ wg = reinterpret_cast<const h4f*>(wshuf + (size_t)m * K * 128);
        h4f* __restrict__ wl = reinterpret_cast<h4f*>(wt);
        for (int idx = t; idx < WH4; idx += 256) wl[idx] = wg[idx];
        __syncthreads();

        f32x4 acc[8];
#pragma unroll
        for (int c = 0; c < 8; ++c) acc[c] = {0, 0, 0, 0};
#pragma unroll
        for (int c = 0; c < 8; ++c)
#pragma unroll
            for (int s = 0; s < KS; ++s) {
                h4f af = wl[(s * 8 + c) * 64 + lane];
                acc[c] = __builtin_amdgcn_mfma_f32_16x16x16f16(af, b[s], acc[c], 0, 0, 0);
            }
        if (node < NN) {
            const float* bm = bias[m];
#pragma unroll
            for (int c = 0; c < 8; ++c) {
                const int hc = c * 16 + hcq;
                const float4 bb = *reinterpret_cast<const float4*>(&bm[hc]);
                float o0 = acc[c][0] + bb.x, o1 = acc[c][1] + bb.y;
                float o2 = acc[c][2] + bb.z, o3 = acc[c][3] + bb.w;
                if (m == 3) {
                    *reinterpret_cast<float4*>(&skout[(size_t)node * 128 + hc]) =
                        make_float4(o0, o1, o2, o3);
                } else {
                    _Float16* dst = (m == 0) ? qout : (m == 1) ? kout : vout;
                    h4f oh = {(_Float16)o0, (_Float16)o1, (_Float16)o2, (_Float16)o3};
                    *reinterpret_cast<h4f*>(&dst[(size_t)node * 128 + hc]) = oh;
                }
            }
        }
        __syncthreads();
    }
}

// ---------------- fused per-node attention aggregation ----------------
// One 64-lane wave per node: 4 x 16-lane edge groups (every-4th edge), 8 ch/lane.
// Branch-free predicated loop; split-softmax merge via shfl_xor(16,32).
//   q.e = ea.(we_h @ q) precomputed;  sum(a~*e) = we @ T (T online-rescaled)
__global__ __launch_bounds__(256, 8) void node_agg(
    const int* __restrict__ rowptr, const int4* __restrict__ edges,
    const _Float16* __restrict__ qh, const _Float16* __restrict__ kh,
    const _Float16* __restrict__ vh, const float* __restrict__ we,
    const float* __restrict__ sk, _Float16* __restrict__ houth, int relu)
{
    __shared__ float we_s[4 * 128];
    const int t = threadIdx.x;
    if (t < 128)
        reinterpret_cast<float4*>(we_s)[t] = reinterpret_cast<const float4*>(we)[t];
    __syncthreads();
    const int node = blockIdx.x * 4 + (t >> 6);
    if (node >= NN) return;
    const int lane = t & 63;
    const int g = lane >> 4, sub = lane & 15, ch0 = sub * 8;
    const int beg = rowptr[node], end = rowptr[node + 1];
    const int deg = end - beg;

    // q scaled by (1/sqrt(32))*log2(e): exp2 domain, exact reassociation
    const float sc = 0.17677669529663687f * 1.4426950408889634f;
    const h8f q8 = *reinterpret_cast<const h8f*>(&qh[(size_t)node * 128 + ch0]);
    float qf[8];
#pragma unroll
    for (int j = 0; j < 8; ++j) qf[j] = (float)q8[j] * sc;

    float qe[4];
#pragma unroll
    for (int d = 0; d < 4; ++d) {
        float pq = 0.f;
#pragma unroll
        for (int j = 0; j < 8; ++j) pq += we_s[d * 128 + ch0 + j] * qf[j];
        pq += __shfl_xor(pq, 1); pq += __shfl_xor(pq, 2);
        qe[d] = pq;
    }

    float m = -1e38f, s = 0.f;
    float acc[8] = {0, 0, 0, 0, 0, 0, 0, 0};
    float T[4] = {0, 0, 0, 0};

    const int nt = (deg + 3) >> 2;
    int p = beg + g;
    for (int i = 0; i < nt; ++i, p += 4) {
        const bool act = p < end;
        const int pc = act ? p : beg;
        const int4 r = edges[pc];
        EU u; u.i = make_int2(r.y, r.z);
        const h8f k8 = *reinterpret_cast<const h8f*>(&kh[(size_t)r.x * 128 + ch0]);
        const h8f v8 = *reinterpret_cast<const h8f*>(&vh[(size_t)r.x * 128 + ch0]);
        float al = 0.f;
#pragma unroll
        for (int j = 0; j < 8; ++j) al += qf[j] * (float)k8[j];
        al += __shfl_xor(al, 1); al += __shfl_xor(al, 2);   // 4-lane head reduce
        const float f0 = (float)u.h[0], f1 = (float)u.h[1],
                    f2 = (float)u.h[2], f3 = (float)u.h[3];
        al += f0 * qe[0] + f1 * qe[1] + f2 * qe[2] + f3 * qe[3];
        al = act ? al : -1e38f;
        const float mn = fmaxf(m, al);
        const float rr = exp2f(m - mn);
        const float pe = exp2f(al - mn);
        s = s * rr + pe;
#pragma unroll
        for (int j = 0; j < 8; ++j) acc[j] = acc[j] * rr + pe * (float)v8[j];
        T[0] = T[0] * rr + pe * f0; T[1] = T[1] * rr + pe * f1;
        T[2] = T[2] * rr + pe * f2; T[3] = T[3] * rr + pe * f3;
        m = mn;
    }

    // merge the 4 group states (exact split-softmax merge)
#pragma unroll
    for (int off = 16; off <= 32; off <<= 1) {
        const float mo = __shfl_xor(m, off);
        const float so = __shfl_xor(s, off);
        const float mn = fmaxf(m, mo);
        const float r1 = exp2f(m - mn), r2 = exp2f(mo - mn);
        s = s * r1 + so * r2;
#pragma unroll
        for (int j = 0; j < 8; ++j) {
            const float ao = __shfl_xor(acc[j], off);
            acc[j] = acc[j] * r1 + ao * r2;
        }
#pragma unroll
        for (int d = 0; d < 4; ++d) {
            const float To = __shfl_xor(T[d], off);
            T[d] = T[d] * r1 + To * r2;
        }
        m = mn;
    }

    if (g == 0) {
        const float inv = 1.0f / (s + 1e-16f);
        const float4 s0 = *reinterpret_cast<const float4*>(&sk[(size_t)node * 128 + ch0]);
        const float4 s1 = *reinterpret_cast<const float4*>(&sk[(size_t)node * 128 + ch0 + 4]);
        const float skv[8] = {s0.x, s0.y, s0.z, s0.w, s1.x, s1.y, s1.z, s1.w};
        h8f oh;
#pragma unroll
        for (int j = 0; j < 8; ++j) {
            const float wT = we_s[0 * 128 + ch0 + j] * T[0] + we_s[1 * 128 + ch0 + j] * T[1]
                           + we_s[2 * 128 + ch0 + j] * T[2] + we_s[3 * 128 + ch0 + j] * T[3];
            float ov = (acc[j] + wT) * inv + skv[j];
            if (relu) ov = fmaxf(ov, 0.f);
            oh[j] = (_Float16)ov;
        }
        *reinterpret_cast<h8f*>(&houth[(size_t)node * 128 + ch0]) = oh;
    }
}

// ---------------- pooling + head (batch is sorted; h in f16) ----------------

__global__ __launch_bounds__(256) void boundaries_k(const int* __restrict__ batch,
                                                    int* __restrict__ gptr)
{
    int i = blockIdx.x * 256 + threadIdx.x;
    if (i >= NN) return;
    int b = batch[i];
    int bp = (i == 0) ? -1 : batch[i - 1];
    for (int g = bp + 1; g <= b; ++g) gptr[g] = i;
    if (i == NN - 1) for (int g = b + 1; g <= GG; ++g) gptr[g] = NN;
}

__global__ __launch_bounds__(128) void head_k(
    const _Float16* __restrict__ h, const int* __restrict__ gptr,
    const float* __restrict__ wlin, const float* __restrict__ blin,
    float* __restrict__ out)
{
    __shared__ float red[128];
    const int g = blockIdx.x;
    const int t = threadIdx.x;
    const int beg = gptr[g], end = gptr[g + 1];
    float p = 0.f;
    for (int n = beg; n < end; ++n) p += (float)h[(size_t)n * 128 + t];
    p *= wlin[t];
    red[t] = p;
    __syncthreads();
    for (int off = 64; off; off >>= 1) {
        if (t < off) red[t] += red[t + off];
        __syncthreads();
    }
    if (t == 0) out[g] = red[0] / fmaxf((float)(end - beg), 1.0f) + blin[0];
}

extern "C" void kernel_launch(void* const* d_in, const int* in_sizes, int n_in,
                              void* d_out, int out_size, void* d_ws, size_t ws_size,
                              hipStream_t stream)
{
    const float* x     = (const float*)d_in[0];
    const int*   ei    = (const int*)d_in[1];
    const float* ea    = (const float*)d_in[2];
    const int*   batch = (const int*)d_in[3];
    auto W = [&](int i) { return (const float*)d_in[i]; };

    char* wsb = (char*)d_ws;
    size_t off = 0;
    auto alloc = [&](size_t bytes) { void* p = wsb + off; off += (bytes + 15) & ~15ull; return p; };

    float* sk       = (float*)alloc((size_t)NN * 128 * 4);
    int4*  edges    = (int4*)alloc((size_t)EE * 16);
    _Float16* qh    = (_Float16*)alloc((size_t)NN * 128 * 2);
    _Float16* kh    = (_Float16*)alloc((size_t)NN * 128 * 2);
    _Float16* vh    = (_Float16*)alloc((size_t)NN * 128 * 2);
    _Float16* hh    = (_Float16*)alloc((size_t)NN * 128 * 2);
    _Float16* wshuf = (_Float16*)alloc(((size_t)4 * 64 * 128 + 8 * 128 * 128) * 2);
    int* cnt    = (int*)alloc((size_t)NN * 4);
    int* rowptr = (int*)alloc((size_t)(NN + 1) * 4);
    int* wcur   = (int*)alloc((size_t)NN * 4);
    int* gptr   = (int*)alloc((size_t)(GG + 1) * 4);
    int* bsum   = (int*)alloc((size_t)64 * 4);

    // ---- CSR build + packed edge records (recomputed each call; deterministic) ----
    hipMemsetAsync(cnt, 0, NN * sizeof(int), stream);
    hist_k<<<ceil_div(EE, 256), 256, 0, stream>>>(ei, cnt);
    const int NB = ceil_div(NN, 1024);
    scan1_k<<<NB, 1024, 0, stream>>>(cnt, NN, rowptr, bsum);
    scan2_k<<<1, 64, 0, stream>>>(bsum, NB);
    scan3_k<<<NB, 1024, 0, stream>>>(rowptr, wcur, bsum, NN);
    scatter_k<<<ceil_div(EE, 256), 256, 0, stream>>>(ei, (const float4*)ea, wcur, edges);

    boundaries_k<<<ceil_div(NN, 256), 256, 0, stream>>>(batch, gptr);

    W12 w12 = {{ W(4), W(6), W(8), W(11),
                 W(13), W(15), W(17), W(20),
                 W(22), W(24), W(26), W(29) }};
    shuffle_w12<<<dim3(64, 12), 64, 0, stream>>>(w12, wshuf);
    const size_t wsz1 = (size_t)4 * 64 * 128;
    const size_t wsz2 = (size_t)4 * 128 * 128;

    auto layer = [&](int K, const void* xin, const _Float16* wsh, int relu, int wb) {
        if (K == 64)
            gemm_mfma<64, true><<<ceil_div(NN, 64), 256, 0, stream>>>(
                xin, wsh, W(wb + 1), W(wb + 3), W(wb + 5), W(wb + 8), qh, kh, vh, sk);
        else
            gemm_mfma<128, false><<<ceil_div(NN, 64), 256, 0, stream>>>(
                xin, wsh, W(wb + 1), W(wb + 3), W(wb + 5), W(wb + 8), qh, kh, vh, sk);
        node_agg<<<ceil_div(NN, 4), 256, 0, stream>>>(
            rowptr, edges, qh, kh, vh, W(wb + 6), sk, hh, relu);
    };

    layer(64,  x,  wshuf, 1, 4);
    layer(128, hh, wshuf + wsz1, 1, 13);
    layer(128, hh, wshuf + wsz1 + wsz2, 0, 22);

    head_k<<<GG, 128, 0, stream>>>(hh, gptr, W(31), W(32), (float*)d_out);
}

// Round 8
// 466.449 us; speedup vs baseline: 1.1387x; 1.0242x over previous
//
#include <hip/hip_runtime.h>
#include <math.h>

#define NN 50000
#define EE 800000
#define GG 1000

typedef __attribute__((ext_vector_type(2))) _Float16 h2f;
typedef __attribute__((ext_vector_type(4))) _Float16 h4f;
typedef __attribute__((ext_vector_type(8))) _Float16 h8f;
typedef __attribute__((ext_vector_type(4))) float f32x4;

#if __has_builtin(__builtin_amdgcn_fdot2)
#define FDOT2(a, b, c) __builtin_amdgcn_fdot2((a), (b), (c), false)
#else
#define FDOT2(a, b, c) ((float)(a)[0] * (float)(b)[0] + (float)(a)[1] * (float)(b)[1] + (c))
#endif

static inline int ceil_div(int a, int b) { return (a + b - 1) / b; }

union EU { int2 i; h4f h; };

// ---------------- counting-sort of edges by dst (packed 16B records) ----------------

__global__ __launch_bounds__(256) void hist_k(const int* __restrict__ ei, int* __restrict__ cnt)
{
    int e = blockIdx.x * 256 + threadIdx.x;
    if (e >= EE) return;
    atomicAdd(&cnt[ei[EE + e]], 1);
}

__global__ __launch_bounds__(1024) void scan1_k(const int* __restrict__ cnt, int n,
                                                int* __restrict__ rowptr, int* __restrict__ bsum)
{
    __shared__ int tmp[1024];
    const int tid = threadIdx.x;
    const int i = blockIdx.x * 1024 + tid;
    tmp[tid] = (i < n) ? cnt[i] : 0;
    __syncthreads();
    for (int off = 1; off < 1024; off <<= 1) {
        int t = (tid >= off) ? tmp[tid - off] : 0;
        __syncthreads();
        tmp[tid] += t;
        __syncthreads();
    }
    if (i < n) rowptr[i + 1] = tmp[tid];
    if (tid == 1023) bsum[blockIdx.x] = tmp[1023];
}

__global__ __launch_bounds__(64) void scan2_k(int* __restrict__ bsum, int nb)
{
    const int t = threadIdx.x;
    int v = (t < nb) ? bsum[t] : 0;
    const int orig = v;
    for (int off = 1; off < 64; off <<= 1) {
        int n = __shfl_up(v, off);
        if (t >= off) v += n;
    }
    if (t < nb) bsum[t] = v - orig;   // exclusive prefix
}

__global__ __launch_bounds__(1024) void scan3_k(int* __restrict__ rowptr,
                                                int* __restrict__ wcur,
                                                const int* __restrict__ bsum, int n)
{
    int i = blockIdx.x * 1024 + threadIdx.x;
    if (i < n) {
        int v = rowptr[i + 1] + bsum[blockIdx.x];
        rowptr[i + 1] = v;
        if (i + 1 < n) wcur[i + 1] = v;
    }
    if (i == 0) { rowptr[0] = 0; wcur[0] = 0; }
}

__global__ __launch_bounds__(256) void scatter_k(const int* __restrict__ ei,
                                                 const float4* __restrict__ ea,
                                                 int* __restrict__ wcur,
                                                 int4* __restrict__ edges)
{
    int e = blockIdx.x * 256 + threadIdx.x;
    if (e >= EE) return;
    int dst = ei[EE + e];
    int pos = atomicAdd(&wcur[dst], 1);
    float4 a = ea[e];
    EU u; u.h = h4f{(_Float16)a.x, (_Float16)a.y, (_Float16)a.z, (_Float16)a.w};
    edges[pos] = make_int4(ei[e], u.i.x, u.i.y, 0);
}

// ---------------- weight shuffle: all 12 matrices in one launch ----------------
struct W12 { const float* w[12]; };

__global__ __launch_bounds__(64) void shuffle_w12(W12 ws, _Float16* __restrict__ out)
{
    const int m = blockIdx.y;
    const int K = (m < 4) ? 64 : 128;
    const int nblk = (K / 16) * 8;
    if (blockIdx.x >= nblk) return;
    const int s = blockIdx.x >> 3, c16 = blockIdx.x & 7;
    const int lane = threadIdx.x;
    const float* __restrict__ w = ws.w[m];
    const int kbase = s * 16 + (lane >> 4) * 4;
    const int col = c16 * 16 + (lane & 15);
    h4f h;
#pragma unroll
    for (int j = 0; j < 4; ++j) h[j] = (_Float16)w[(size_t)(kbase + j) * 128 + col];
    size_t base = (m < 4) ? (size_t)m * 64 * 128
                          : (size_t)4 * 64 * 128 + (size_t)(m - 4) * 128 * 128;
    reinterpret_cast<h4f*>(out + base)[(size_t)blockIdx.x * 64 + lane] = h;
}

// ---------------- fused 4-matrix MFMA GEMM (LDS x-tile + LDS weight tile) ----------------
template<int K, bool F32IN>
__global__ __launch_bounds__(256) void gemm_mfma(
    const void* __restrict__ xin, const _Float16* __restrict__ wshuf,
    const float* __restrict__ bq, const float* __restrict__ bk,
    const float* __restrict__ bv, const float* __restrict__ bs,
    _Float16* __restrict__ qout, _Float16* __restrict__ kout,
    _Float16* __restrict__ vout, float* __restrict__ skout)
{
    constexpr int KS = K / 16;
    constexpr int PADK = K + 8;
    __shared__ _Float16 xs[64 * PADK];
    __shared__ _Float16 wt[K * 128];
    const int t = threadIdx.x;
    const int bn = blockIdx.x * 64;
    if (F32IN) {
        const float* xf = (const float*)xin;
        constexpr int C4 = K / 4;
        for (int idx = t; idx < 64 * C4; idx += 256) {
            const int row = idx / C4, c4 = idx % C4;
            float4 val = make_float4(0.f, 0.f, 0.f, 0.f);
            if (bn + row < NN)
                val = reinterpret_cast<const float4*>(xf)[(size_t)(bn + row) * C4 + c4];
            h4f h = {(_Float16)val.x, (_Float16)val.y, (_Float16)val.z, (_Float16)val.w};
            *reinterpret_cast<h4f*>(&xs[row * PADK + c4 * 4]) = h;
        }
    } else {
        const _Float16* xh = (const _Float16*)xin;
        constexpr int CH = K / 8;
        for (int idx = t; idx < 64 * CH; idx += 256) {
            const int row = idx / CH, ch = idx % CH;
            h8f val = {0, 0, 0, 0, 0, 0, 0, 0};
            if (bn + row < NN)
                val = reinterpret_cast<const h8f*>(xh + (size_t)(bn + row) * K)[ch];
            *reinterpret_cast<h8f*>(&xs[row * PADK + ch * 8]) = val;
        }
    }
    __syncthreads();

    const int wid = t >> 6, lane = t & 63;
    const int rloc = wid * 16 + (lane & 15);
    const int ko = (lane >> 4) * 4;
    h4f b[KS];
#pragma unroll
    for (int s = 0; s < KS; ++s)
        b[s] = *reinterpret_cast<const h4f*>(&xs[rloc * PADK + s * 16 + ko]);

    const int node = bn + rloc;
    const int hcq = (lane >> 4) * 4;
    const float* bias[4] = {bq, bk, bv, bs};
    constexpr int WH4 = K * 128 / 4;

#pragma unroll
    for (int m = 0; m < 4; ++m) {
        const h4f* __restrict__ wg = reinterpret_cast<const h4f*>(wshuf + (size_t)m * K * 128);
        h4f* __restrict__ wl = reinterpret_cast<h4f*>(wt);
        for (int idx = t; idx < WH4; idx += 256) wl[idx] = wg[idx];
        __syncthreads();

        f32x4 acc[8];
#pragma unroll
        for (int c = 0; c < 8; ++c) acc[c] = {0, 0, 0, 0};
#pragma unroll
        for (int c = 0; c < 8; ++c)
#pragma unroll
            for (int s = 0; s < KS; ++s) {
                h4f af = wl[(s * 8 + c) * 64 + lane];
                acc[c] = __builtin_amdgcn_mfma_f32_16x16x16f16(af, b[s], acc[c], 0, 0, 0);
            }
        if (node < NN) {
            const float* bm = bias[m];
#pragma unroll
            for (int c = 0; c < 8; ++c) {
                const int hc = c * 16 + hcq;
                const float4 bb = *reinterpret_cast<const float4*>(&bm[hc]);
                float o0 = acc[c][0] + bb.x, o1 = acc[c][1] + bb.y;
                float o2 = acc[c][2] + bb.z, o3 = acc[c][3] + bb.w;
                if (m == 3) {
                    *reinterpret_cast<float4*>(&skout[(size_t)node * 128 + hc]) =
                        make_float4(o0, o1, o2, o3);
                } else {
                    _Float16* dst = (m == 0) ? qout : (m == 1) ? kout : vout;
                    h4f oh = {(_Float16)o0, (_Float16)o1, (_Float16)o2, (_Float16)o3};
                    *reinterpret_cast<h4f*>(&dst[(size_t)node * 128 + hc]) = oh;
                }
            }
        }
        __syncthreads();
    }
}

// ---------------- fused per-node attention aggregation ----------------
// One 64-lane wave per node: 4 x 16-lane edge groups (every-4th edge), 8 ch/lane.
// fdot2 for q.k; defer-max online softmax (rescale only on __any(al > m+10));
// split-softmax merge via shfl_xor(16,32). q.e precomputed; sum(a~*e) = we @ T.
__global__ __launch_bounds__(256, 8) void node_agg(
    const int* __restrict__ rowptr, const int4* __restrict__ edges,
    const _Float16* __restrict__ qh, const _Float16* __restrict__ kh,
    const _Float16* __restrict__ vh, const float* __restrict__ we,
    const float* __restrict__ sk, _Float16* __restrict__ houth, int relu)
{
    __shared__ float we_s[4 * 128];
    const int t = threadIdx.x;
    if (t < 128)
        reinterpret_cast<float4*>(we_s)[t] = reinterpret_cast<const float4*>(we)[t];
    __syncthreads();
    const int node = blockIdx.x * 4 + (t >> 6);
    if (node >= NN) return;
    const int lane = t & 63;
    const int g = lane >> 4, sub = lane & 15, ch0 = sub * 8;
    const int beg = rowptr[node], end = rowptr[node + 1];
    const int deg = end - beg;

    // q pre-scaled by (1/sqrt(32))*log2(e), kept f32 for qe and packed f16 for fdot2
    const float sc = 0.17677669529663687f * 1.4426950408889634f;
    const h8f q8 = *reinterpret_cast<const h8f*>(&qh[(size_t)node * 128 + ch0]);
    float qf[8];
#pragma unroll
    for (int j = 0; j < 8; ++j) qf[j] = (float)q8[j] * sc;
    h2f qp[4];
#pragma unroll
    for (int i = 0; i < 4; ++i) {
        qp[i][0] = (_Float16)qf[2 * i];
        qp[i][1] = (_Float16)qf[2 * i + 1];
    }

    // qe[d] = sum_{c in head} we[d][c] * qscaled[c]   (4-lane head-subgroup reduce)
    float qe[4];
#pragma unroll
    for (int d = 0; d < 4; ++d) {
        const float4 wa = *reinterpret_cast<const float4*>(&we_s[d * 128 + ch0]);
        const float4 wb = *reinterpret_cast<const float4*>(&we_s[d * 128 + ch0 + 4]);
        float pq = wa.x * qf[0] + wa.y * qf[1] + wa.z * qf[2] + wa.w * qf[3]
                 + wb.x * qf[4] + wb.y * qf[5] + wb.z * qf[6] + wb.w * qf[7];
        pq += __shfl_xor(pq, 1); pq += __shfl_xor(pq, 2);
        qe[d] = pq;
    }

    float m = -1e30f, s = 0.f;
    float acc[8] = {0, 0, 0, 0, 0, 0, 0, 0};
    float T[4] = {0, 0, 0, 0};

    const int nt = (deg + 3) >> 2;
    int p = beg + g;
    for (int i = 0; i < nt; ++i, p += 4) {
        const bool act = p < end;
        const int4 r = edges[act ? p : beg];
        const int4 ki = *reinterpret_cast<const int4*>(&kh[(size_t)r.x * 128 + ch0]);
        const int4 vi = *reinterpret_cast<const int4*>(&vh[(size_t)r.x * 128 + ch0]);
        float al = FDOT2(qp[0], __builtin_bit_cast(h2f, ki.x), 0.0f);
        al = FDOT2(qp[1], __builtin_bit_cast(h2f, ki.y), al);
        al = FDOT2(qp[2], __builtin_bit_cast(h2f, ki.z), al);
        al = FDOT2(qp[3], __builtin_bit_cast(h2f, ki.w), al);
        al += __shfl_xor(al, 1); al += __shfl_xor(al, 2);   // 4-lane head reduce
        const h2f e01 = __builtin_bit_cast(h2f, r.y);
        const h2f e23 = __builtin_bit_cast(h2f, r.z);
        const float f0 = (float)e01[0], f1 = (float)e01[1];
        const float f2 = (float)e23[0], f3 = (float)e23[1];
        al += f0 * qe[0] + f1 * qe[1] + f2 * qe[2] + f3 * qe[3];
        al = act ? al : -1e30f;
        // defer-max: rescale only when some lane's al exceeds m + 10 (pe <= 2^10)
        if (__any(al > m + 10.0f)) {
            const float mn = fmaxf(m, al);
            const float rr = exp2f(m - mn);
            s *= rr;
#pragma unroll
            for (int j = 0; j < 8; ++j) acc[j] *= rr;
#pragma unroll
            for (int d = 0; d < 4; ++d) T[d] *= rr;
            m = mn;
        }
        const float pe = exp2f(al - m);
        s += pe;
        const h2f v01 = __builtin_bit_cast(h2f, vi.x);
        const h2f v23 = __builtin_bit_cast(h2f, vi.y);
        const h2f v45 = __builtin_bit_cast(h2f, vi.z);
        const h2f v67 = __builtin_bit_cast(h2f, vi.w);
        acc[0] += pe * (float)v01[0]; acc[1] += pe * (float)v01[1];
        acc[2] += pe * (float)v23[0]; acc[3] += pe * (float)v23[1];
        acc[4] += pe * (float)v45[0]; acc[5] += pe * (float)v45[1];
        acc[6] += pe * (float)v67[0]; acc[7] += pe * (float)v67[1];
        T[0] += pe * f0; T[1] += pe * f1; T[2] += pe * f2; T[3] += pe * f3;
    }

    // merge the 4 group states (exact split-softmax merge)
#pragma unroll
    for (int off = 16; off <= 32; off <<= 1) {
        const float mo = __shfl_xor(m, off);
        const float so = __shfl_xor(s, off);
        const float mn = fmaxf(m, mo);
        const float r1 = exp2f(m - mn), r2 = exp2f(mo - mn);
        s = s * r1 + so * r2;
#pragma unroll
        for (int j = 0; j < 8; ++j) {
            const float ao = __shfl_xor(acc[j], off);
            acc[j] = acc[j] * r1 + ao * r2;
        }
#pragma unroll
        for (int d = 0; d < 4; ++d) {
            const float To = __shfl_xor(T[d], off);
            T[d] = T[d] * r1 + To * r2;
        }
        m = mn;
    }

    if (g == 0) {
        const float inv = 1.0f / (s + 1e-16f);
        float4 wa[4], wb[4];
#pragma unroll
        for (int d = 0; d < 4; ++d) {
            wa[d] = *reinterpret_cast<const float4*>(&we_s[d * 128 + ch0]);
            wb[d] = *reinterpret_cast<const float4*>(&we_s[d * 128 + ch0 + 4]);
        }
        const float4 s0 = *reinterpret_cast<const float4*>(&sk[(size_t)node * 128 + ch0]);
        const float4 s1 = *reinterpret_cast<const float4*>(&sk[(size_t)node * 128 + ch0 + 4]);
        float ov[8];
        ov[0] = (acc[0] + wa[0].x * T[0] + wa[1].x * T[1] + wa[2].x * T[2] + wa[3].x * T[3]) * inv + s0.x;
        ov[1] = (acc[1] + wa[0].y * T[0] + wa[1].y * T[1] + wa[2].y * T[2] + wa[3].y * T[3]) * inv + s0.y;
        ov[2] = (acc[2] + wa[0].z * T[0] + wa[1].z * T[1] + wa[2].z * T[2] + wa[3].z * T[3]) * inv + s0.z;
        ov[3] = (acc[3] + wa[0].w * T[0] + wa[1].w * T[1] + wa[2].w * T[2] + wa[3].w * T[3]) * inv + s0.w;
        ov[4] = (acc[4] + wb[0].x * T[0] + wb[1].x * T[1] + wb[2].x * T[2] + wb[3].x * T[3]) * inv + s1.x;
        ov[5] = (acc[5] + wb[0].y * T[0] + wb[1].y * T[1] + wb[2].y * T[2] + wb[3].y * T[3]) * inv + s1.y;
        ov[6] = (acc[6] + wb[0].z * T[0] + wb[1].z * T[1] + wb[2].z * T[2] + wb[3].z * T[3]) * inv + s1.z;
        ov[7] = (acc[7] + wb[0].w * T[0] + wb[1].w * T[1] + wb[2].w * T[2] + wb[3].w * T[3]) * inv + s1.w;
        h8f oh;
#pragma unroll
        for (int j = 0; j < 8; ++j) {
            float v = relu ? fmaxf(ov[j], 0.f) : ov[j];
            oh[j] = (_Float16)v;
        }
        *reinterpret_cast<h8f*>(&houth[(size_t)node * 128 + ch0]) = oh;
    }
}

// ---------------- pooling + head (batch is sorted; h in f16) ----------------

__global__ __launch_bounds__(256) void boundaries_k(const int* __restrict__ batch,
                                                    int* __restrict__ gptr)
{
    int i = blockIdx.x * 256 + threadIdx.x;
    if (i >= NN) return;
    int b = batch[i];
    int bp = (i == 0) ? -1 : batch[i - 1];
    for (int g = bp + 1; g <= b; ++g) gptr[g] = i;
    if (i == NN - 1) for (int g = b + 1; g <= GG; ++g) gptr[g] = NN;
}

__global__ __launch_bounds__(128) void head_k(
    const _Float16* __restrict__ h, const int* __restrict__ gptr,
    const float* __restrict__ wlin, const float* __restrict__ blin,
    float* __restrict__ out)
{
    __shared__ float red[128];
    const int g = blockIdx.x;
    const int t = threadIdx.x;
    const int beg = gptr[g], end = gptr[g + 1];
    float p = 0.f;
    for (int n = beg; n < end; ++n) p += (float)h[(size_t)n * 128 + t];
    p *= wlin[t];
    red[t] = p;
    __syncthreads();
    for (int off = 64; off; off >>= 1) {
        if (t < off) red[t] += red[t + off];
        __syncthreads();
    }
    if (t == 0) out[g] = red[0] / fmaxf((float)(end - beg), 1.0f) + blin[0];
}

extern "C" void kernel_launch(void* const* d_in, const int* in_sizes, int n_in,
                              void* d_out, int out_size, void* d_ws, size_t ws_size,
                              hipStream_t stream)
{
    const float* x     = (const float*)d_in[0];
    const int*   ei    = (const int*)d_in[1];
    const float* ea    = (const float*)d_in[2];
    const int*   batch = (const int*)d_in[3];
    auto W = [&](int i) { return (const float*)d_in[i]; };

    char* wsb = (char*)d_ws;
    size_t off = 0;
    auto alloc = [&](size_t bytes) { void* p = wsb + off; off += (bytes + 15) & ~15ull; return p; };

    float* sk       = (float*)alloc((size_t)NN * 128 * 4);
    int4*  edges    = (int4*)alloc((size_t)EE * 16);
    _Float16* qh    = (_Float16*)alloc((size_t)NN * 128 * 2);
    _Float16* kh    = (_Float16*)alloc((size_t)NN * 128 * 2);
    _Float16* vh    = (_Float16*)alloc((size_t)NN * 128 * 2);
    _Float16* hh    = (_Float16*)alloc((size_t)NN * 128 * 2);
    _Float16* wshuf = (_Float16*)alloc(((size_t)4 * 64 * 128 + 8 * 128 * 128) * 2);
    int* cnt    = (int*)alloc((size_t)NN * 4);
    int* rowptr = (int*)alloc((size_t)(NN + 1) * 4);
    int* wcur   = (int*)alloc((size_t)NN * 4);
    int* gptr   = (int*)alloc((size_t)(GG + 1) * 4);
    int* bsum   = (int*)alloc((size_t)64 * 4);

    // ---- CSR build + packed edge records (recomputed each call; deterministic) ----
    hipMemsetAsync(cnt, 0, NN * sizeof(int), stream);
    hist_k<<<ceil_div(EE, 256), 256, 0, stream>>>(ei, cnt);
    const int NB = ceil_div(NN, 1024);
    scan1_k<<<NB, 1024, 0, stream>>>(cnt, NN, rowptr, bsum);
    scan2_k<<<1, 64, 0, stream>>>(bsum, NB);
    scan3_k<<<NB, 1024, 0, stream>>>(rowptr, wcur, bsum, NN);
    scatter_k<<<ceil_div(EE, 256), 256, 0, stream>>>(ei, (const float4*)ea, wcur, edges);

    boundaries_k<<<ceil_div(NN, 256), 256, 0, stream>>>(batch, gptr);

    W12 w12 = {{ W(4), W(6), W(8), W(11),
                 W(13), W(15), W(17), W(20),
                 W(22), W(24), W(26), W(29) }};
    shuffle_w12<<<dim3(64, 12), 64, 0, stream>>>(w12, wshuf);
    const size_t wsz1 = (size_t)4 * 64 * 128;
    const size_t wsz2 = (size_t)4 * 128 * 128;

    auto layer = [&](int K, const void* xin, const _Float16* wsh, int relu, int wb) {
        if (K == 64)
            gemm_mfma<64, true><<<ceil_div(NN, 64), 256, 0, stream>>>(
                xin, wsh, W(wb + 1), W(wb + 3), W(wb + 5), W(wb + 8), qh, kh, vh, sk);
        else
            gemm_mfma<128, false><<<ceil_div(NN, 64), 256, 0, stream>>>(
                xin, wsh, W(wb + 1), W(wb + 3), W(wb + 5), W(wb + 8), qh, kh, vh, sk);
        node_agg<<<ceil_div(NN, 4), 256, 0, stream>>>(
            rowptr, edges, qh, kh, vh, W(wb + 6), sk, hh, relu);
    };

    layer(64,  x,  wshuf, 1, 4);
    layer(128, hh, wshuf + wsz1, 1, 13);
    layer(128, hh, wshuf + wsz1 + wsz2, 0, 22);

    head_k<<<GG, 128, 0, stream>>>(hh, gptr, W(31), W(32), (float*)d_out);
}